// Round 3
// baseline (617.192 us; speedup 1.0000x reference)
//
#include <hip/hip_runtime.h>

// Weird_Attention — exact algebraic restructure:
//   last = glb_probs @ (gv + softmax(pq pk^T/8) @ pv)
// => 6 proj GEMMs (batched, 1 dispatch) -> flash-attn(plb) -> v'=gv+plb
//    -> flash-attn(glb, v') -> dense GEMM.
// R1 changes: P-LDS XOR swizzle (was 16-way conflicted), no-max softmax
// (shift-invariant, logits bounded), scale*log2e folded into q-projection,
// K register prefetch + early V issue, P double-buffer, launch_bounds cap.
// R2: fix missing (float*) cast on d_out.

#define DEVI static __device__ __forceinline__

typedef __attribute__((ext_vector_type(4))) float f32x4;
typedef __attribute__((ext_vector_type(8))) __bf16 bf16x8;
typedef __attribute__((ext_vector_type(8))) short s16x8;
typedef __attribute__((ext_vector_type(4))) short s16x4;

constexpr int S = 1024, D = 1024, NH = 16, DH = 64, NB = 4;
constexpr int M = NB * S;
constexpr int KD = 1024;
constexpr int ND = 1024;
constexpr float QSCALE = 0.18033688011112042f;   // log2(e)/8

#define EXP2(x) exp2f(x)

DEVI short f2bf(float f) {
  unsigned u = __builtin_bit_cast(unsigned, f);
  u += 0x7FFFu + ((u >> 16) & 1u);   // RNE
  return (short)(u >> 16);
}

DEVI f32x4 mfma_bf16(s16x8 a, s16x8 b, f32x4 c) {
  return __builtin_amdgcn_mfma_f32_16x16x32_bf16(
      __builtin_bit_cast(bf16x8, a), __builtin_bit_cast(bf16x8, b), c, 0, 0, 0);
}

DEVI void gll16(const void* g, void* l) {
  __builtin_amdgcn_global_load_lds(
      (const __attribute__((address_space(1))) unsigned*)g,
      (__attribute__((address_space(3))) unsigned*)l, 16, 0, 0);
}

// ---------------- casts ----------------
struct Ptrs3 { const float* p0; const float* p1; const float* p2; };
struct Ptrs7 { const float* p[7]; };

__global__ __launch_bounds__(256) void cast_inputs(Ptrs3 in, short* __restrict__ out) {
  int b = blockIdx.x;                       // 3 * 4096 blocks
  int which = b >> 12;
  const float* src = which == 0 ? in.p0 : (which == 1 ? in.p1 : in.p2);
  size_t local = ((size_t)(b & 4095) * 256 + threadIdx.x) * 4;
  f32x4 v = *(const f32x4*)(src + local);
  s16x4 o = { f2bf(v[0]), f2bf(v[1]), f2bf(v[2]), f2bf(v[3]) };
  *(s16x4*)(out + (size_t)which * ((size_t)M * KD) + local) = o;
}

__global__ __launch_bounds__(256) void cast_weights(Ptrs7 in, short* __restrict__ out) {
  int b = blockIdx.x;                       // 7 * 1024 blocks
  int which = b >> 10;
  size_t local = ((size_t)(b & 1023) * 256 + threadIdx.x) * 4;
  f32x4 v = *(const f32x4*)(in.p[which] + local);
  s16x4 o = { f2bf(v[0]), f2bf(v[1]), f2bf(v[2]), f2bf(v[3]) };
  *(s16x4*)(out + (size_t)which * 1048576 + local) = o;
}

// ------- batched projection GEMM: 6 C[M,N] = A@W^T + b in one dispatch -------
// z selects {A, W, bias, out, mode, scale}. 128x128 tile, BK=32, 4 waves.
struct GemmBatch {
  const short* A[6];
  const float* bias[6];
  void* out[6];
};

__global__ __launch_bounds__(256) void gemm_proj(GemmBatch gb, const short* __restrict__ W) {
  __shared__ short As[128 * 32];
  __shared__ short Bs[128 * 32];
  const int z = blockIdx.z;
  const short* A = gb.A[z];
  const short* Bw = W + (size_t)z * ((size_t)KD * ND);
  const float* bias = gb.bias[z];
  const float scale = (z == 0 || z == 3) ? QSCALE : 1.0f;
  const int f32out = (z == 2);

  const int tid = threadIdx.x;
  const int lane = tid & 63, wave = tid >> 6;
  const int wr = wave >> 1, wc = wave & 1;
  const int l15 = lane & 15, lg = lane >> 4;
  const int rowBase = blockIdx.y * 128, colBase = blockIdx.x * 128;

  const int cr = tid >> 2, co = (tid & 3) * 8;
  const short* gA0 = A + (size_t)(rowBase + cr) * KD + co;
  const short* gA1 = A + (size_t)(rowBase + 64 + cr) * KD + co;
  const short* gB0 = Bw + (size_t)(colBase + cr) * KD + co;
  const short* gB1 = Bw + (size_t)(colBase + 64 + cr) * KD + co;
  short* lA0 = As + tid * 8;
  short* lA1 = As + (tid + 256) * 8;
  short* lB0 = Bs + tid * 8;
  short* lB1 = Bs + (tid + 256) * 8;

  f32x4 acc[4][4] = {};
  for (int k0 = 0; k0 < KD; k0 += 32) {
    __syncthreads();
    gll16(gA0 + k0, lA0);
    gll16(gA1 + k0, lA1);
    gll16(gB0 + k0, lB0);
    gll16(gB1 + k0, lB1);
    __syncthreads();
    s16x8 af[4], bf[4];
#pragma unroll
    for (int m = 0; m < 4; m++)
      af[m] = *(const s16x8*)(As + (wr * 64 + m * 16 + l15) * 32 + lg * 8);
#pragma unroll
    for (int n = 0; n < 4; n++)
      bf[n] = *(const s16x8*)(Bs + (wc * 64 + n * 16 + l15) * 32 + lg * 8);
#pragma unroll
    for (int m = 0; m < 4; m++)
#pragma unroll
      for (int n = 0; n < 4; n++)
        acc[m][n] = mfma_bf16(af[m], bf[n], acc[m][n]);
  }

  const int r0 = lg * 4;
#pragma unroll
  for (int m = 0; m < 4; m++)
#pragma unroll
    for (int n = 0; n < 4; n++)
#pragma unroll
      for (int i = 0; i < 4; i++) {
        int row = rowBase + wr * 64 + m * 16 + r0 + i;
        int col = colBase + wc * 64 + n * 16 + l15;
        float v = (acc[m][n][i] + bias[col]) * scale;
        size_t idx = (((size_t)(row >> 10) * NH + (col >> 6)) * S + (row & (S - 1))) * DH + (col & (DH - 1));
        if (f32out) ((float*)gb.out[z])[idx] = v;
        else        ((short*)gb.out[z])[idx] = f2bf(v);
      }
}

// ---------------- dense GEMM: f32 [M,N] = A@W^T + b ----------------
__global__ __launch_bounds__(256) void gemm_dense(const short* __restrict__ A,
                                                  const short* __restrict__ Bw,
                                                  const float* __restrict__ bias,
                                                  float* __restrict__ outp) {
  __shared__ short As[128 * 32];
  __shared__ short Bs[128 * 32];
  const int tid = threadIdx.x;
  const int lane = tid & 63, wave = tid >> 6;
  const int wr = wave >> 1, wc = wave & 1;
  const int l15 = lane & 15, lg = lane >> 4;
  const int rowBase = blockIdx.y * 128, colBase = blockIdx.x * 128;

  const int cr = tid >> 2, co = (tid & 3) * 8;
  const short* gA0 = A + (size_t)(rowBase + cr) * KD + co;
  const short* gA1 = A + (size_t)(rowBase + 64 + cr) * KD + co;
  const short* gB0 = Bw + (size_t)(colBase + cr) * KD + co;
  const short* gB1 = Bw + (size_t)(colBase + 64 + cr) * KD + co;
  short* lA0 = As + tid * 8;
  short* lA1 = As + (tid + 256) * 8;
  short* lB0 = Bs + tid * 8;
  short* lB1 = Bs + (tid + 256) * 8;

  f32x4 acc[4][4] = {};
  for (int k0 = 0; k0 < KD; k0 += 32) {
    __syncthreads();
    gll16(gA0 + k0, lA0);
    gll16(gA1 + k0, lA1);
    gll16(gB0 + k0, lB0);
    gll16(gB1 + k0, lB1);
    __syncthreads();
    s16x8 af[4], bf[4];
#pragma unroll
    for (int m = 0; m < 4; m++)
      af[m] = *(const s16x8*)(As + (wr * 64 + m * 16 + l15) * 32 + lg * 8);
#pragma unroll
    for (int n = 0; n < 4; n++)
      bf[n] = *(const s16x8*)(Bs + (wc * 64 + n * 16 + l15) * 32 + lg * 8);
#pragma unroll
    for (int m = 0; m < 4; m++)
#pragma unroll
      for (int n = 0; n < 4; n++)
        acc[m][n] = mfma_bf16(af[m], bf[n], acc[m][n]);
  }

  const int r0 = lg * 4;
#pragma unroll
  for (int m = 0; m < 4; m++)
#pragma unroll
    for (int n = 0; n < 4; n++)
#pragma unroll
      for (int i = 0; i < 4; i++) {
        int row = rowBase + wr * 64 + m * 16 + r0 + i;
        int col = colBase + wc * 64 + n * 16 + l15;
        outp[(size_t)row * ND + col] = acc[m][n][i] + bias[col];
      }
}

// ---------------- transpose [BH,S,64] bf16 -> [BH,64,S] bf16 ----------------
__global__ __launch_bounds__(256) void transpose_bf16(const short* __restrict__ in,
                                                      short* __restrict__ out) {
  __shared__ short t[64 * 65];
  const int bh = blockIdx.y, s0 = blockIdx.x * 64;
  const int tid = threadIdx.x;
#pragma unroll
  for (int j = 0; j < 16; j++) {
    int e = j * 256 + tid;
    int s = e >> 6, d = e & 63;
    t[d * 65 + s] = in[((size_t)bh * S + s0 + s) * DH + d];
  }
  __syncthreads();
#pragma unroll
  for (int j = 0; j < 16; j++) {
    int e = j * 256 + tid;
    int d = e >> 6, s = e & 63;
    out[((size_t)bh * DH + d) * S + s0 + s] = t[d * 65 + s];
  }
}

// v' = bf16(gv + plb_attn), transposed to [BH,64,S]
__global__ __launch_bounds__(256) void vprime_t(const float* __restrict__ gv,
                                                const float* __restrict__ pa,
                                                short* __restrict__ out) {
  __shared__ short t[64 * 65];
  const int bh = blockIdx.y, s0 = blockIdx.x * 64;
  const int tid = threadIdx.x;
#pragma unroll
  for (int j = 0; j < 16; j++) {
    int e = j * 256 + tid;
    int s = e >> 6, d = e & 63;
    size_t idx = ((size_t)bh * S + s0 + s) * DH + d;
    t[d * 65 + s] = f2bf(gv[idx] + pa[idx]);
  }
  __syncthreads();
#pragma unroll
  for (int j = 0; j < 16; j++) {
    int e = j * 256 + tid;
    int d = e >> 6, s = e & 63;
    out[((size_t)bh * DH + d) * S + s0 + s] = t[d * 65 + s];
  }
}

// ---------------- flash attention (no-max softmax) ----------------
// Q bf16 [BH,S,64] PRE-SCALED by log2(e)/8; K bf16 [BH,S,64]; Vt bf16 [BH,64,S].
// 4 waves/block, 16 q-rows/wave, 64-key tiles. p = exp2(s); O = acc / sum(p).
// Exact: softmax is shift/base invariant; |logits| bounded (no overflow).
// OUTMODE 0: f32 [BH,S,64]; 1: bf16 merged [B,S,D].
template <int OUTMODE>
__global__ __launch_bounds__(256, 4) void attn64(const short* __restrict__ Q,
                                                 const short* __restrict__ Km,
                                                 const short* __restrict__ Vt,
                                                 void* __restrict__ outp) {
  __shared__ short Pl[4 * 2 * 1024];   // per-wave double-buffered 16x64 P tile
  const int tid = threadIdx.x, lane = tid & 63, wave = tid >> 6;
  const int l15 = lane & 15, lg = lane >> 4;
  const int bh = blockIdx.y;
  const int q0 = blockIdx.x * 64 + wave * 16;

  const short* qp = Q + ((size_t)bh * S + q0 + l15) * DH + lg * 8;
  s16x8 qf0 = *(const s16x8*)qp;
  s16x8 qf1 = *(const s16x8*)(qp + 32);

  const short* kb = Km + (size_t)bh * S * DH;
  const short* vb = Vt + (size_t)bh * DH * S;
  short* Pbase = Pl + wave * 2048;
  const int swz = (l15 & 7) << 3;      // read-side XOR (units of shorts)

  // preload K tile 0
  s16x8 kf[4][2];
#pragma unroll
  for (int n = 0; n < 4; n++) {
    const short* kp = kb + (size_t)(n * 16 + l15) * DH + lg * 8;
    kf[n][0] = *(const s16x8*)kp;
    kf[n][1] = *(const s16x8*)(kp + 32);
  }

  f32x4 acc[4] = {};
  float lrow[4] = {0.f, 0.f, 0.f, 0.f};

  for (int kt = 0; kt < S; kt += 64) {
    // V tile loads — issued early, consumed at PV
    s16x8 vf[4][2];
#pragma unroll
    for (int n = 0; n < 4; n++) {
      const short* vp = vb + (size_t)(n * 16 + l15) * S + kt + lg * 8;
      vf[n][0] = *(const s16x8*)vp;
      vf[n][1] = *(const s16x8*)(vp + 32);
    }
    // QK^T on preloaded K
    f32x4 sf[4];
#pragma unroll
    for (int n = 0; n < 4; n++) {
      sf[n] = mfma_bf16(qf0, kf[n][0], f32x4{});
      sf[n] = mfma_bf16(qf1, kf[n][1], sf[n]);
    }
    // prefetch next K tile into the now-dead kf regs
    if (kt + 64 < S) {
#pragma unroll
      for (int n = 0; n < 4; n++) {
        const short* kp = kb + (size_t)(kt + 64 + n * 16 + l15) * DH + lg * 8;
        kf[n][0] = *(const s16x8*)kp;
        kf[n][1] = *(const s16x8*)(kp + 32);
      }
    }
    // p = 2^s  (scale folded into Q projection); row-sum over keys
    f32x4 p[4];
    float ts[4];
#pragma unroll
    for (int n = 0; n < 4; n++)
#pragma unroll
      for (int i = 0; i < 4; i++) p[n][i] = EXP2(sf[n][i]);
#pragma unroll
    for (int i = 0; i < 4; i++) ts[i] = (p[0][i] + p[1][i]) + (p[2][i] + p[3][i]);
#pragma unroll
    for (int off = 1; off < 16; off <<= 1)
#pragma unroll
      for (int i = 0; i < 4; i++) ts[i] += __shfl_xor(ts[i], off);
#pragma unroll
    for (int i = 0; i < 4; i++) lrow[i] += ts[i];

    // P (C-layout, row=q col=key) -> swizzled LDS -> A-layout fragments
    short* myP = Pbase + ((kt >> 6) & 1) * 1024;
#pragma unroll
    for (int n = 0; n < 4; n++)
#pragma unroll
      for (int i = 0; i < 4; i++) {
        int row = lg * 4 + i;
        myP[row * 64 + ((n * 16 + l15) ^ ((row & 7) << 3))] = f2bf(p[n][i]);
      }
    asm volatile("s_waitcnt lgkmcnt(0)" ::: "memory");
    s16x8 pa0 = *(const s16x8*)(myP + l15 * 64 + ((lg * 8) ^ swz));
    s16x8 pa1 = *(const s16x8*)(myP + l15 * 64 + ((32 + lg * 8) ^ swz));

#pragma unroll
    for (int n = 0; n < 4; n++) {
      acc[n] = mfma_bf16(pa0, vf[n][0], acc[n]);
      acc[n] = mfma_bf16(pa1, vf[n][1], acc[n]);
    }
  }

  float inv[4];
#pragma unroll
  for (int i = 0; i < 4; i++) inv[i] = 1.f / lrow[i];
#pragma unroll
  for (int n = 0; n < 4; n++)
#pragma unroll
    for (int i = 0; i < 4; i++) {
      int qq = q0 + lg * 4 + i;
      int dc = n * 16 + l15;
      float v = acc[n][i] * inv[i];
      if (OUTMODE == 0)
        ((float*)outp)[((size_t)bh * S + qq) * DH + dc] = v;
      else
        ((short*)outp)[((size_t)(bh >> 4) * S + qq) * D + (bh & 15) * DH + dc] = f2bf(v);
    }
}

// ---------------- launch ----------------
extern "C" void kernel_launch(void* const* d_in, const int* in_sizes, int n_in,
                              void* d_out, int out_size, void* d_ws, size_t ws_size,
                              hipStream_t stream) {
  const float* xg = (const float*)d_in[0];
  const float* xl = (const float*)d_in[1];
  const float* xt = (const float*)d_in[2];
  const float* wf[7]; const float* bf_[7];
  for (int i = 0; i < 7; i++) { wf[i] = (const float*)d_in[3 + 2 * i]; bf_[i] = (const float*)d_in[4 + 2 * i]; }

  char* ws = (char*)d_ws;
  size_t off = 0;
  auto alloc = [&](size_t bytes) { void* p = ws + off; off += (bytes + 255) & ~(size_t)255; return p; };
  short* x16   = (short*)alloc((size_t)3 * M * KD * 2);
  short* w16   = (short*)alloc((size_t)7 * KD * ND * 2);
  short* gq16  = (short*)alloc((size_t)M * D * 2);
  short* gk16  = (short*)alloc((size_t)M * D * 2);
  float* gv32  = (float*)alloc((size_t)M * D * 4);
  short* pq16  = (short*)alloc((size_t)M * D * 2);
  short* pk16  = (short*)alloc((size_t)M * D * 2);
  short* pv16  = (short*)alloc((size_t)M * D * 2);
  short* pvt16 = (short*)alloc((size_t)M * D * 2);
  float* plb32 = (float*)alloc((size_t)M * D * 4);
  short* vpt16 = (short*)alloc((size_t)M * D * 2);
  short* last16= (short*)alloc((size_t)M * D * 2);
  (void)ws_size; (void)in_sizes; (void)n_in; (void)out_size;

  short* xg16 = x16;
  short* xl16 = x16 + (size_t)M * KD;
  short* xt16 = x16 + (size_t)2 * M * KD;

  Ptrs3 p3{xg, xl, xt};
  cast_inputs<<<3 * 4096, 256, 0, stream>>>(p3, x16);
  Ptrs7 p7; for (int i = 0; i < 7; i++) p7.p[i] = wf[i];
  cast_weights<<<7 * 1024, 256, 0, stream>>>(p7, w16);

  // Batched 6 projections: z = {gq*, gk, gv(f32), pq*, pk, pv}  (* = Q-scaled)
  GemmBatch gb;
  gb.A[0] = xg16; gb.A[1] = xl16; gb.A[2] = xl16; gb.A[3] = xl16; gb.A[4] = xt16; gb.A[5] = xt16;
  for (int i = 0; i < 6; i++) gb.bias[i] = bf_[i];
  gb.out[0] = gq16; gb.out[1] = gk16; gb.out[2] = gv32;
  gb.out[3] = pq16; gb.out[4] = pk16; gb.out[5] = pv16;
  dim3 gg(ND / 128, M / 128, 6);   // 1536 blocks = 6/CU
  gemm_proj<<<gg, 256, 0, stream>>>(gb, w16);

  dim3 gt(S / 64, NB * NH);        // (16, 64)
  transpose_bf16<<<gt, 256, 0, stream>>>(pv16, pvt16);
  attn64<0><<<gt, 256, 0, stream>>>(pq16, pk16, pvt16, plb32);     // plb_attn
  vprime_t<<<gt, 256, 0, stream>>>(gv32, plb32, vpt16);            // v' = gv + plb
  attn64<1><<<gt, 256, 0, stream>>>(gq16, gk16, vpt16, last16);    // last (merged)

  dim3 gd(ND / 128, M / 128);      // (8, 32)
  gemm_dense<<<gd, 256, 0, stream>>>(last16, w16 + (size_t)6 * 1048576, bf_[6], (float*)d_out);
}

// Round 4
// 357.855 us; speedup vs baseline: 1.7247x; 1.7247x over previous
//
#include <hip/hip_runtime.h>

// Weird_Attention — exact algebraic restructure:
//   last = glb_probs @ (gv + softmax(pq pk^T/8) @ pv)
// => 6 proj GEMMs (batched) -> flash-attn(plb) -> v'=gv+plb
//    -> flash-attn(glb, v') -> dense GEMM.
// R3 post-mortem: R1's register K/V prefetch spilled to scratch
// (WRITE_SIZE 16->42MB proved it). R4: K/V staged in LDS via global_load_lds
// (shared across waves, linear dest + pre-swizzled source + swizzled reads),
// double-buffered; XCD-aware block swizzle so each head lives on one XCD L2.

#define DEVI static __device__ __forceinline__

typedef __attribute__((ext_vector_type(4))) float f32x4;
typedef __attribute__((ext_vector_type(8))) __bf16 bf16x8;
typedef __attribute__((ext_vector_type(8))) short s16x8;
typedef __attribute__((ext_vector_type(4))) short s16x4;

constexpr int S = 1024, D = 1024, NH = 16, DH = 64, NB = 4;
constexpr int M = NB * S;
constexpr int KD = 1024;
constexpr int ND = 1024;
constexpr float QSCALE = 0.18033688011112042f;   // log2(e)/8

DEVI short f2bf(float f) {
  unsigned u = __builtin_bit_cast(unsigned, f);
  u += 0x7FFFu + ((u >> 16) & 1u);   // RNE
  return (short)(u >> 16);
}

DEVI f32x4 mfma_bf16(s16x8 a, s16x8 b, f32x4 c) {
  return __builtin_amdgcn_mfma_f32_16x16x32_bf16(
      __builtin_bit_cast(bf16x8, a), __builtin_bit_cast(bf16x8, b), c, 0, 0, 0);
}

DEVI void gll16(const void* g, void* l) {
  __builtin_amdgcn_global_load_lds(
      (const __attribute__((address_space(1))) unsigned*)g,
      (__attribute__((address_space(3))) unsigned*)l, 16, 0, 0);
}

// ---------------- casts ----------------
struct Ptrs3 { const float* p0; const float* p1; const float* p2; };
struct Ptrs7 { const float* p[7]; };

__global__ __launch_bounds__(256) void cast_inputs(Ptrs3 in, short* __restrict__ out) {
  int b = blockIdx.x;                       // 3 * 4096 blocks
  int which = b >> 12;
  const float* src = which == 0 ? in.p0 : (which == 1 ? in.p1 : in.p2);
  size_t local = ((size_t)(b & 4095) * 256 + threadIdx.x) * 4;
  f32x4 v = *(const f32x4*)(src + local);
  s16x4 o = { f2bf(v[0]), f2bf(v[1]), f2bf(v[2]), f2bf(v[3]) };
  *(s16x4*)(out + (size_t)which * ((size_t)M * KD) + local) = o;
}

__global__ __launch_bounds__(256) void cast_weights(Ptrs7 in, short* __restrict__ out) {
  int b = blockIdx.x;                       // 7 * 1024 blocks
  int which = b >> 10;
  size_t local = ((size_t)(b & 1023) * 256 + threadIdx.x) * 4;
  f32x4 v = *(const f32x4*)(in.p[which] + local);
  s16x4 o = { f2bf(v[0]), f2bf(v[1]), f2bf(v[2]), f2bf(v[3]) };
  *(s16x4*)(out + (size_t)which * 1048576 + local) = o;
}

// ------- batched projection GEMM: 6 C[M,N] = A@W^T + b in one dispatch -------
struct GemmBatch {
  const short* A[6];
  const float* bias[6];
  void* out[6];
};

__global__ __launch_bounds__(256) void gemm_proj(GemmBatch gb, const short* __restrict__ W) {
  __shared__ short As[128 * 32];
  __shared__ short Bs[128 * 32];
  const int z = blockIdx.z;
  const short* A = gb.A[z];
  const short* Bw = W + (size_t)z * ((size_t)KD * ND);
  const float* bias = gb.bias[z];
  const float scale = (z == 0 || z == 3) ? QSCALE : 1.0f;
  const int f32out = (z == 2);

  const int tid = threadIdx.x;
  const int lane = tid & 63, wave = tid >> 6;
  const int wr = wave >> 1, wc = wave & 1;
  const int l15 = lane & 15, lg = lane >> 4;
  const int rowBase = blockIdx.y * 128, colBase = blockIdx.x * 128;

  const int cr = tid >> 2, co = (tid & 3) * 8;
  const short* gA0 = A + (size_t)(rowBase + cr) * KD + co;
  const short* gA1 = A + (size_t)(rowBase + 64 + cr) * KD + co;
  const short* gB0 = Bw + (size_t)(colBase + cr) * KD + co;
  const short* gB1 = Bw + (size_t)(colBase + 64 + cr) * KD + co;
  short* lA0 = As + tid * 8;
  short* lA1 = As + (tid + 256) * 8;
  short* lB0 = Bs + tid * 8;
  short* lB1 = Bs + (tid + 256) * 8;

  f32x4 acc[4][4] = {};
  for (int k0 = 0; k0 < KD; k0 += 32) {
    __syncthreads();
    gll16(gA0 + k0, lA0);
    gll16(gA1 + k0, lA1);
    gll16(gB0 + k0, lB0);
    gll16(gB1 + k0, lB1);
    __syncthreads();
    s16x8 af[4], bf[4];
#pragma unroll
    for (int m = 0; m < 4; m++)
      af[m] = *(const s16x8*)(As + (wr * 64 + m * 16 + l15) * 32 + lg * 8);
#pragma unroll
    for (int n = 0; n < 4; n++)
      bf[n] = *(const s16x8*)(Bs + (wc * 64 + n * 16 + l15) * 32 + lg * 8);
#pragma unroll
    for (int m = 0; m < 4; m++)
#pragma unroll
      for (int n = 0; n < 4; n++)
        acc[m][n] = mfma_bf16(af[m], bf[n], acc[m][n]);
  }

  const int r0 = lg * 4;
#pragma unroll
  for (int m = 0; m < 4; m++)
#pragma unroll
    for (int n = 0; n < 4; n++)
#pragma unroll
      for (int i = 0; i < 4; i++) {
        int row = rowBase + wr * 64 + m * 16 + r0 + i;
        int col = colBase + wc * 64 + n * 16 + l15;
        float v = (acc[m][n][i] + bias[col]) * scale;
        size_t idx = (((size_t)(row >> 10) * NH + (col >> 6)) * S + (row & (S - 1))) * DH + (col & (DH - 1));
        if (f32out) ((float*)gb.out[z])[idx] = v;
        else        ((short*)gb.out[z])[idx] = f2bf(v);
      }
}

// ---------------- dense GEMM: f32 [M,N] = A@W^T + b ----------------
__global__ __launch_bounds__(256) void gemm_dense(const short* __restrict__ A,
                                                  const short* __restrict__ Bw,
                                                  const float* __restrict__ bias,
                                                  float* __restrict__ outp) {
  __shared__ short As[128 * 32];
  __shared__ short Bs[128 * 32];
  const int tid = threadIdx.x;
  const int lane = tid & 63, wave = tid >> 6;
  const int wr = wave >> 1, wc = wave & 1;
  const int l15 = lane & 15, lg = lane >> 4;
  const int rowBase = blockIdx.y * 128, colBase = blockIdx.x * 128;

  const int cr = tid >> 2, co = (tid & 3) * 8;
  const short* gA0 = A + (size_t)(rowBase + cr) * KD + co;
  const short* gA1 = A + (size_t)(rowBase + 64 + cr) * KD + co;
  const short* gB0 = Bw + (size_t)(colBase + cr) * KD + co;
  const short* gB1 = Bw + (size_t)(colBase + 64 + cr) * KD + co;
  short* lA0 = As + tid * 8;
  short* lA1 = As + (tid + 256) * 8;
  short* lB0 = Bs + tid * 8;
  short* lB1 = Bs + (tid + 256) * 8;

  f32x4 acc[4][4] = {};
  for (int k0 = 0; k0 < KD; k0 += 32) {
    __syncthreads();
    gll16(gA0 + k0, lA0);
    gll16(gA1 + k0, lA1);
    gll16(gB0 + k0, lB0);
    gll16(gB1 + k0, lB1);
    __syncthreads();
    s16x8 af[4], bf[4];
#pragma unroll
    for (int m = 0; m < 4; m++)
      af[m] = *(const s16x8*)(As + (wr * 64 + m * 16 + l15) * 32 + lg * 8);
#pragma unroll
    for (int n = 0; n < 4; n++)
      bf[n] = *(const s16x8*)(Bs + (wc * 64 + n * 16 + l15) * 32 + lg * 8);
#pragma unroll
    for (int m = 0; m < 4; m++)
#pragma unroll
      for (int n = 0; n < 4; n++)
        acc[m][n] = mfma_bf16(af[m], bf[n], acc[m][n]);
  }

  const int r0 = lg * 4;
#pragma unroll
  for (int m = 0; m < 4; m++)
#pragma unroll
    for (int n = 0; n < 4; n++)
#pragma unroll
      for (int i = 0; i < 4; i++) {
        int row = rowBase + wr * 64 + m * 16 + r0 + i;
        int col = colBase + wc * 64 + n * 16 + l15;
        outp[(size_t)row * ND + col] = acc[m][n][i] + bias[col];
      }
}

// ---------------- transpose [BH,S,64] bf16 -> [BH,64,S] bf16 ----------------
__global__ __launch_bounds__(256) void transpose_bf16(const short* __restrict__ in,
                                                      short* __restrict__ out) {
  __shared__ short t[64 * 65];
  const int bh = blockIdx.y, s0 = blockIdx.x * 64;
  const int tid = threadIdx.x;
#pragma unroll
  for (int j = 0; j < 16; j++) {
    int e = j * 256 + tid;
    int s = e >> 6, d = e & 63;
    t[d * 65 + s] = in[((size_t)bh * S + s0 + s) * DH + d];
  }
  __syncthreads();
#pragma unroll
  for (int j = 0; j < 16; j++) {
    int e = j * 256 + tid;
    int d = e >> 6, s = e & 63;
    out[((size_t)bh * DH + d) * S + s0 + s] = t[d * 65 + s];
  }
}

// v' = bf16(gv + plb_attn), transposed to [BH,64,S]
__global__ __launch_bounds__(256) void vprime_t(const float* __restrict__ gv,
                                                const float* __restrict__ pa,
                                                short* __restrict__ out) {
  __shared__ short t[64 * 65];
  const int bh = blockIdx.y, s0 = blockIdx.x * 64;
  const int tid = threadIdx.x;
#pragma unroll
  for (int j = 0; j < 16; j++) {
    int e = j * 256 + tid;
    int s = e >> 6, d = e & 63;
    size_t idx = ((size_t)bh * S + s0 + s) * DH + d;
    t[d * 65 + s] = f2bf(gv[idx] + pa[idx]);
  }
  __syncthreads();
#pragma unroll
  for (int j = 0; j < 16; j++) {
    int e = j * 256 + tid;
    int d = e >> 6, s = e & 63;
    out[((size_t)bh * DH + d) * S + s0 + s] = t[d * 65 + s];
  }
}

// ---------------- flash attention (no-max softmax, LDS-staged K/V) ----------
// Q bf16 [BH,S,64] PRE-SCALED by log2(e)/8; K bf16 [BH,S,64]; Vt bf16 [BH,64,S].
// 4 waves/block (16 q-rows each), 64-key tiles. p = exp2(s); O = acc/sum(p).
// K/V tiles double-buffered in LDS via global_load_lds: linear dest,
// pre-swizzled global source (XOR byte^((row&7)<<4)), swizzled frag reads.
// XCD swizzle: 8 whole heads per XCD -> K/V fit 4MB L2.
// Stage K tile [64 rows][128B] and V^T tile [64 dh][128B] for this kt.
DEVI void stage_kv(const short* kb, const short* vb, int kt,
                   short* KT, short* VTs, int tid) {
  const int r0 = tid >> 3, cb = (tid & 7) * 16;
  const int r1 = r0 + 32;
  const int sw0 = (r0 & 7) << 4;   // r1&7 == r0&7
  gll16((const char*)kb + (size_t)(kt + r0) * 128 + (cb ^ sw0), KT + tid * 8);
  gll16((const char*)kb + (size_t)(kt + r1) * 128 + (cb ^ sw0), KT + (tid + 256) * 8);
  gll16((const char*)vb + (size_t)r0 * 2048 + (size_t)kt * 2 + (cb ^ sw0), VTs + tid * 8);
  gll16((const char*)vb + (size_t)r1 * 2048 + (size_t)kt * 2 + (cb ^ sw0), VTs + (tid + 256) * 8);
}

template <int OUTMODE>
__global__ __launch_bounds__(256, 4) void attn64(const short* __restrict__ Q,
                                                 const short* __restrict__ Km,
                                                 const short* __restrict__ Vt,
                                                 void* __restrict__ outp) {
  __shared__ short KT[2][64 * 64];
  __shared__ short VTs[2][64 * 64];
  __shared__ short Pl[4][1024];
  const int tid = threadIdx.x, lane = tid & 63, wave = tid >> 6;
  const int l15 = lane & 15, lg = lane >> 4;
  // XCD swizzle: nwg=1024, xcd k gets heads [k*8, k*8+8)
  const int w = blockIdx.x;
  const int sw = (w & 7) * 128 + (w >> 3);
  const int bh = sw >> 4;
  const int q0 = (sw & 15) * 64 + wave * 16;

  const short* qp = Q + ((size_t)bh * S + q0 + l15) * DH + lg * 8;
  s16x8 qf0 = *(const s16x8*)qp;
  s16x8 qf1 = *(const s16x8*)(qp + 32);

  const short* kb = Km + (size_t)bh * S * DH;
  const short* vb = Vt + (size_t)bh * DH * S;
  short* myP = Pl[wave];
  const int rsz = (l15 & 7) << 3;   // frag-read XOR in shorts

  stage_kv(kb, vb, 0, KT[0], VTs[0], tid);
  __syncthreads();

  f32x4 acc[4] = {};
  float lrow[4] = {0.f, 0.f, 0.f, 0.f};

  for (int kt = 0; kt < S; kt += 64) {
    const int cur = (kt >> 6) & 1;
    if (kt + 64 < S) stage_kv(kb, vb, kt + 64, KT[cur ^ 1], VTs[cur ^ 1], tid);

    // QK^T from LDS K tile (swizzled reads, conflict-free)
    f32x4 sf[4];
#pragma unroll
    for (int n = 0; n < 4; n++) {
      const short* kr = KT[cur] + (n * 16 + l15) * 64;
      s16x8 k0 = *(const s16x8*)(kr + ((lg * 8) ^ rsz));
      s16x8 k1 = *(const s16x8*)(kr + ((32 + lg * 8) ^ rsz));
      sf[n] = mfma_bf16(qf0, k0, f32x4{});
      sf[n] = mfma_bf16(qf1, k1, sf[n]);
    }

    // p = 2^s (scale folded into Q projection); row-sum over keys
    f32x4 p[4];
    float ts[4];
#pragma unroll
    for (int n = 0; n < 4; n++)
#pragma unroll
      for (int i = 0; i < 4; i++) p[n][i] = exp2f(sf[n][i]);
#pragma unroll
    for (int i = 0; i < 4; i++) ts[i] = (p[0][i] + p[1][i]) + (p[2][i] + p[3][i]);
#pragma unroll
    for (int off = 1; off < 16; off <<= 1)
#pragma unroll
      for (int i = 0; i < 4; i++) ts[i] += __shfl_xor(ts[i], off);
#pragma unroll
    for (int i = 0; i < 4; i++) lrow[i] += ts[i];

    // P (C-layout) -> swizzled wave-private LDS -> A-layout fragments
#pragma unroll
    for (int n = 0; n < 4; n++)
#pragma unroll
      for (int i = 0; i < 4; i++) {
        int row = lg * 4 + i;
        myP[row * 64 + ((n * 16 + l15) ^ ((row & 7) << 3))] = f2bf(p[n][i]);
      }
    asm volatile("s_waitcnt lgkmcnt(0)" ::: "memory");
    s16x8 pa0 = *(const s16x8*)(myP + l15 * 64 + ((lg * 8) ^ rsz));
    s16x8 pa1 = *(const s16x8*)(myP + l15 * 64 + ((32 + lg * 8) ^ rsz));

    // PV from LDS V^T tile
#pragma unroll
    for (int n = 0; n < 4; n++) {
      const short* vr = VTs[cur] + (n * 16 + l15) * 64;
      s16x8 v0 = *(const s16x8*)(vr + ((lg * 8) ^ rsz));
      s16x8 v1 = *(const s16x8*)(vr + ((32 + lg * 8) ^ rsz));
      acc[n] = mfma_bf16(pa0, v0, acc[n]);
      acc[n] = mfma_bf16(pa1, v1, acc[n]);
    }

    __syncthreads();   // stage(next) drained + all waves done with buf[cur]
  }

  float inv[4];
#pragma unroll
  for (int i = 0; i < 4; i++) inv[i] = 1.f / lrow[i];
#pragma unroll
  for (int n = 0; n < 4; n++)
#pragma unroll
    for (int i = 0; i < 4; i++) {
      int qq = q0 + lg * 4 + i;
      int dc = n * 16 + l15;
      float v = acc[n][i] * inv[i];
      if (OUTMODE == 0)
        ((float*)outp)[((size_t)bh * S + qq) * DH + dc] = v;
      else
        ((short*)outp)[((size_t)(bh >> 4) * S + qq) * D + (bh & 15) * DH + dc] = f2bf(v);
    }
}

// ---------------- launch ----------------
extern "C" void kernel_launch(void* const* d_in, const int* in_sizes, int n_in,
                              void* d_out, int out_size, void* d_ws, size_t ws_size,
                              hipStream_t stream) {
  const float* xg = (const float*)d_in[0];
  const float* xl = (const float*)d_in[1];
  const float* xt = (const float*)d_in[2];
  const float* wf[7]; const float* bf_[7];
  for (int i = 0; i < 7; i++) { wf[i] = (const float*)d_in[3 + 2 * i]; bf_[i] = (const float*)d_in[4 + 2 * i]; }

  char* ws = (char*)d_ws;
  size_t off = 0;
  auto alloc = [&](size_t bytes) { void* p = ws + off; off += (bytes + 255) & ~(size_t)255; return p; };
  short* x16   = (short*)alloc((size_t)3 * M * KD * 2);
  short* w16   = (short*)alloc((size_t)7 * KD * ND * 2);
  short* gq16  = (short*)alloc((size_t)M * D * 2);
  short* gk16  = (short*)alloc((size_t)M * D * 2);
  float* gv32  = (float*)alloc((size_t)M * D * 4);
  short* pq16  = (short*)alloc((size_t)M * D * 2);
  short* pk16  = (short*)alloc((size_t)M * D * 2);
  short* pv16  = (short*)alloc((size_t)M * D * 2);
  short* pvt16 = (short*)alloc((size_t)M * D * 2);
  float* plb32 = (float*)alloc((size_t)M * D * 4);
  short* vpt16 = (short*)alloc((size_t)M * D * 2);
  short* last16= (short*)alloc((size_t)M * D * 2);
  (void)ws_size; (void)in_sizes; (void)n_in; (void)out_size;

  short* xg16 = x16;
  short* xl16 = x16 + (size_t)M * KD;
  short* xt16 = x16 + (size_t)2 * M * KD;

  Ptrs3 p3{xg, xl, xt};
  cast_inputs<<<3 * 4096, 256, 0, stream>>>(p3, x16);
  Ptrs7 p7; for (int i = 0; i < 7; i++) p7.p[i] = wf[i];
  cast_weights<<<7 * 1024, 256, 0, stream>>>(p7, w16);

  // Batched 6 projections: z = {gq*, gk, gv(f32), pq*, pk, pv}  (* = Q-scaled)
  GemmBatch gb;
  gb.A[0] = xg16; gb.A[1] = xl16; gb.A[2] = xl16; gb.A[3] = xl16; gb.A[4] = xt16; gb.A[5] = xt16;
  for (int i = 0; i < 6; i++) gb.bias[i] = bf_[i];
  gb.out[0] = gq16; gb.out[1] = gk16; gb.out[2] = gv32;
  gb.out[3] = pq16; gb.out[4] = pk16; gb.out[5] = pv16;
  dim3 gg(ND / 128, M / 128, 6);   // 1536 blocks = 6/CU
  gemm_proj<<<gg, 256, 0, stream>>>(gb, w16);

  dim3 gt(S / 64, NB * NH);        // (16, 64)
  transpose_bf16<<<gt, 256, 0, stream>>>(pv16, pvt16);
  attn64<0><<<1024, 256, 0, stream>>>(pq16, pk16, pvt16, plb32);   // plb_attn
  vprime_t<<<gt, 256, 0, stream>>>(gv32, plb32, vpt16);            // v' = gv + plb
  attn64<1><<<1024, 256, 0, stream>>>(gq16, gk16, vpt16, last16);  // last (merged)

  dim3 gd(ND / 128, M / 128);      // (8, 32)
  gemm_dense<<<gd, 256, 0, stream>>>(last16, w16 + (size_t)6 * 1048576, bf_[6], (float*)d_out);
}

// Round 6
// 326.091 us; speedup vs baseline: 1.8927x; 1.0974x over previous
//
#include <hip/hip_runtime.h>

// Weird_Attention — exact algebraic restructure:
//   last = glb_probs @ (gv + softmax(pq pk^T/8) @ pv)
// => 6 proj GEMMs (batched) -> flash-attn(plb) -> v'=gv+plb
//    -> flash-attn(glb, v') -> dense GEMM.
// R5: GEMMs converted from 1-phase (stage;drain;compute) to 2-phase
// double-buffered (stage(t+1) overlaps compute(t), one barrier/iter);
// LDS read swizzle (byte ^ ((row>>1)&3)<<4) via pre-swizzled gll source
// kills the 8-way frag-read conflict; bijective XCD swizzle on GEMM grids.
// Attn: row-sum via ones-MFMA (removes 16 shfl + adds per tile).
// R6: resubmit (R5 bench failed on infra: container acquisition).

#define DEVI static __device__ __forceinline__

typedef __attribute__((ext_vector_type(4))) float f32x4;
typedef __attribute__((ext_vector_type(8))) __bf16 bf16x8;
typedef __attribute__((ext_vector_type(8))) short s16x8;
typedef __attribute__((ext_vector_type(4))) short s16x4;

constexpr int S = 1024, D = 1024, NH = 16, DH = 64, NB = 4;
constexpr int M = NB * S;
constexpr int KD = 1024;
constexpr int ND = 1024;
constexpr float QSCALE = 0.18033688011112042f;   // log2(e)/8

DEVI short f2bf(float f) {
  unsigned u = __builtin_bit_cast(unsigned, f);
  u += 0x7FFFu + ((u >> 16) & 1u);   // RNE
  return (short)(u >> 16);
}

DEVI f32x4 mfma_bf16(s16x8 a, s16x8 b, f32x4 c) {
  return __builtin_amdgcn_mfma_f32_16x16x32_bf16(
      __builtin_bit_cast(bf16x8, a), __builtin_bit_cast(bf16x8, b), c, 0, 0, 0);
}

DEVI void gll16(const void* g, void* l) {
  __builtin_amdgcn_global_load_lds(
      (const __attribute__((address_space(1))) unsigned*)g,
      (__attribute__((address_space(3))) unsigned*)l, 16, 0, 0);
}

// ---------------- casts ----------------
struct Ptrs3 { const float* p0; const float* p1; const float* p2; };
struct Ptrs7 { const float* p[7]; };

__global__ __launch_bounds__(256) void cast_inputs(Ptrs3 in, short* __restrict__ out) {
  int b = blockIdx.x;                       // 3 * 4096 blocks
  int which = b >> 12;
  const float* src = which == 0 ? in.p0 : (which == 1 ? in.p1 : in.p2);
  size_t local = ((size_t)(b & 4095) * 256 + threadIdx.x) * 4;
  f32x4 v = *(const f32x4*)(src + local);
  s16x4 o = { f2bf(v[0]), f2bf(v[1]), f2bf(v[2]), f2bf(v[3]) };
  *(s16x4*)(out + (size_t)which * ((size_t)M * KD) + local) = o;
}

__global__ __launch_bounds__(256) void cast_weights(Ptrs7 in, short* __restrict__ out) {
  int b = blockIdx.x;                       // 7 * 1024 blocks
  int which = b >> 10;
  size_t local = ((size_t)(b & 1023) * 256 + threadIdx.x) * 4;
  f32x4 v = *(const f32x4*)(in.p[which] + local);
  s16x4 o = { f2bf(v[0]), f2bf(v[1]), f2bf(v[2]), f2bf(v[3]) };
  *(s16x4*)(out + (size_t)which * 1048576 + local) = o;
}

// -------- shared GEMM staging: 128x32 A-tile + 128x32 B-tile, swizzled ------
// LDS content: T[row][c] = G[row][k0 + (c ^ swz(row))], swz bytes = ((row>>1)&3)<<4.
// gll dest is linear (rule: linear dest + inv-swizzled source + swizzled read).
DEVI void stage_ab(const short* A, const short* Bw, int rowBase, int colBase, int k0,
                   short* Asb, short* Bsb, int tid) {
  const int cr = tid >> 2;
  const int cb = (tid & 3) * 16;           // byte chunk within 64B row
  const int sw = ((cr >> 1) & 3) << 4;     // same for cr and cr+64
  gll16((const char*)(A + (size_t)(rowBase + cr) * KD + k0) + (cb ^ sw), Asb + tid * 8);
  gll16((const char*)(A + (size_t)(rowBase + 64 + cr) * KD + k0) + (cb ^ sw), Asb + (tid + 256) * 8);
  gll16((const char*)(Bw + (size_t)(colBase + cr) * KD + k0) + (cb ^ sw), Bsb + tid * 8);
  gll16((const char*)(Bw + (size_t)(colBase + 64 + cr) * KD + k0) + (cb ^ sw), Bsb + (tid + 256) * 8);
}

// ------- batched projection GEMM: 6 C[M,N] = A@W^T + b in one dispatch -------
struct GemmBatch {
  const short* A[6];
  const float* bias[6];
  void* out[6];
};

__global__ __launch_bounds__(256) void gemm_proj(GemmBatch gb, const short* __restrict__ W) {
  __shared__ short As[2][128 * 32];
  __shared__ short Bs[2][128 * 32];
  // bijective XCD swizzle over 1536 blocks (1536%8==0, cpx=192)
  const int wg = (blockIdx.x & 7) * 192 + (blockIdx.x >> 3);
  const int z = wg >> 8;
  const int rem = wg & 255;
  const int rowBase = (rem >> 3) * 128, colBase = (rem & 7) * 128;

  const short* A = gb.A[z];
  const short* Bw = W + (size_t)z * ((size_t)KD * ND);
  const float* bias = gb.bias[z];
  const float scale = (z == 0 || z == 3) ? QSCALE : 1.0f;
  const int f32out = (z == 2);

  const int tid = threadIdx.x;
  const int lane = tid & 63, wave = tid >> 6;
  const int wr = wave >> 1, wc = wave & 1;
  const int l15 = lane & 15, lg = lane >> 4;
  const int rs = ((l15 >> 1) & 3) << 3;    // frag-read XOR (shorts)

  stage_ab(A, Bw, rowBase, colBase, 0, As[0], Bs[0], tid);
  __syncthreads();

  f32x4 acc[4][4] = {};
  int buf = 0;
  for (int k0 = 0; k0 < KD; k0 += 32) {
    if (k0 + 32 < KD)
      stage_ab(A, Bw, rowBase, colBase, k0 + 32, As[buf ^ 1], Bs[buf ^ 1], tid);
    s16x8 af[4], bf[4];
#pragma unroll
    for (int m = 0; m < 4; m++)
      af[m] = *(const s16x8*)(As[buf] + (wr * 64 + m * 16 + l15) * 32 + ((lg * 8) ^ rs));
#pragma unroll
    for (int n = 0; n < 4; n++)
      bf[n] = *(const s16x8*)(Bs[buf] + (wc * 64 + n * 16 + l15) * 32 + ((lg * 8) ^ rs));
#pragma unroll
    for (int m = 0; m < 4; m++)
#pragma unroll
      for (int n = 0; n < 4; n++)
        acc[m][n] = mfma_bf16(af[m], bf[n], acc[m][n]);
    __syncthreads();   // drains stage(t+1); all waves done reading buf
    buf ^= 1;
  }

  const int r0 = lg * 4;
#pragma unroll
  for (int m = 0; m < 4; m++)
#pragma unroll
    for (int n = 0; n < 4; n++)
#pragma unroll
      for (int i = 0; i < 4; i++) {
        int row = rowBase + wr * 64 + m * 16 + r0 + i;
        int col = colBase + wc * 64 + n * 16 + l15;
        float v = (acc[m][n][i] + bias[col]) * scale;
        size_t idx = (((size_t)(row >> 10) * NH + (col >> 6)) * S + (row & (S - 1))) * DH + (col & (DH - 1));
        if (f32out) ((float*)gb.out[z])[idx] = v;
        else        ((short*)gb.out[z])[idx] = f2bf(v);
      }
}

// ---------------- dense GEMM: f32 [M,N] = A@W^T + b ----------------
__global__ __launch_bounds__(256) void gemm_dense(const short* __restrict__ A,
                                                  const short* __restrict__ Bw,
                                                  const float* __restrict__ bias,
                                                  float* __restrict__ outp) {
  __shared__ short As[2][128 * 32];
  __shared__ short Bs[2][128 * 32];
  const int wg = (blockIdx.x & 7) * 32 + (blockIdx.x >> 3);   // 256 blocks
  const int rowBase = (wg >> 3) * 128, colBase = (wg & 7) * 128;

  const int tid = threadIdx.x;
  const int lane = tid & 63, wave = tid >> 6;
  const int wr = wave >> 1, wc = wave & 1;
  const int l15 = lane & 15, lg = lane >> 4;
  const int rs = ((l15 >> 1) & 3) << 3;

  stage_ab(A, Bw, rowBase, colBase, 0, As[0], Bs[0], tid);
  __syncthreads();

  f32x4 acc[4][4] = {};
  int buf = 0;
  for (int k0 = 0; k0 < KD; k0 += 32) {
    if (k0 + 32 < KD)
      stage_ab(A, Bw, rowBase, colBase, k0 + 32, As[buf ^ 1], Bs[buf ^ 1], tid);
    s16x8 af[4], bf[4];
#pragma unroll
    for (int m = 0; m < 4; m++)
      af[m] = *(const s16x8*)(As[buf] + (wr * 64 + m * 16 + l15) * 32 + ((lg * 8) ^ rs));
#pragma unroll
    for (int n = 0; n < 4; n++)
      bf[n] = *(const s16x8*)(Bs[buf] + (wc * 64 + n * 16 + l15) * 32 + ((lg * 8) ^ rs));
#pragma unroll
    for (int m = 0; m < 4; m++)
#pragma unroll
      for (int n = 0; n < 4; n++)
        acc[m][n] = mfma_bf16(af[m], bf[n], acc[m][n]);
    __syncthreads();
    buf ^= 1;
  }

  const int r0 = lg * 4;
#pragma unroll
  for (int m = 0; m < 4; m++)
#pragma unroll
    for (int n = 0; n < 4; n++)
#pragma unroll
      for (int i = 0; i < 4; i++) {
        int row = rowBase + wr * 64 + m * 16 + r0 + i;
        int col = colBase + wc * 64 + n * 16 + l15;
        outp[(size_t)row * ND + col] = acc[m][n][i] + bias[col];
      }
}

// ---------------- transpose [BH,S,64] bf16 -> [BH,64,S] bf16 ----------------
__global__ __launch_bounds__(256) void transpose_bf16(const short* __restrict__ in,
                                                      short* __restrict__ out) {
  __shared__ short t[64 * 65];
  const int bh = blockIdx.y, s0 = blockIdx.x * 64;
  const int tid = threadIdx.x;
#pragma unroll
  for (int j = 0; j < 16; j++) {
    int e = j * 256 + tid;
    int s = e >> 6, d = e & 63;
    t[d * 65 + s] = in[((size_t)bh * S + s0 + s) * DH + d];
  }
  __syncthreads();
#pragma unroll
  for (int j = 0; j < 16; j++) {
    int e = j * 256 + tid;
    int d = e >> 6, s = e & 63;
    out[((size_t)bh * DH + d) * S + s0 + s] = t[d * 65 + s];
  }
}

// v' = bf16(gv + plb_attn), transposed to [BH,64,S]
__global__ __launch_bounds__(256) void vprime_t(const float* __restrict__ gv,
                                                const float* __restrict__ pa,
                                                short* __restrict__ out) {
  __shared__ short t[64 * 65];
  const int bh = blockIdx.y, s0 = blockIdx.x * 64;
  const int tid = threadIdx.x;
#pragma unroll
  for (int j = 0; j < 16; j++) {
    int e = j * 256 + tid;
    int s = e >> 6, d = e & 63;
    size_t idx = ((size_t)bh * S + s0 + s) * DH + d;
    t[d * 65 + s] = f2bf(gv[idx] + pa[idx]);
  }
  __syncthreads();
#pragma unroll
  for (int j = 0; j < 16; j++) {
    int e = j * 256 + tid;
    int d = e >> 6, s = e & 63;
    out[((size_t)bh * DH + d) * S + s0 + s] = t[d * 65 + s];
  }
}

// ---------------- flash attention (no-max softmax, LDS-staged K/V) ----------
// Q bf16 [BH,S,64] PRE-SCALED by log2(e)/8; K bf16 [BH,S,64]; Vt bf16 [BH,64,S].
// 4 waves/block (16 q-rows each), 64-key tiles. p = exp2(s); O = acc/sum(p).
// Row-sum via ones-MFMA: accS = mfma(pa, ones, accS) accumulates sum_k p.
DEVI void stage_kv(const short* kb, const short* vb, int kt,
                   short* KT, short* VTs, int tid) {
  const int r0 = tid >> 3, cb = (tid & 7) * 16;
  const int r1 = r0 + 32;
  const int sw0 = (r0 & 7) << 4;   // r1&7 == r0&7
  gll16((const char*)kb + (size_t)(kt + r0) * 128 + (cb ^ sw0), KT + tid * 8);
  gll16((const char*)kb + (size_t)(kt + r1) * 128 + (cb ^ sw0), KT + (tid + 256) * 8);
  gll16((const char*)vb + (size_t)r0 * 2048 + (size_t)kt * 2 + (cb ^ sw0), VTs + tid * 8);
  gll16((const char*)vb + (size_t)r1 * 2048 + (size_t)kt * 2 + (cb ^ sw0), VTs + (tid + 256) * 8);
}

template <int OUTMODE>
__global__ __launch_bounds__(256, 4) void attn64(const short* __restrict__ Q,
                                                 const short* __restrict__ Km,
                                                 const short* __restrict__ Vt,
                                                 void* __restrict__ outp) {
  __shared__ short KT[2][64 * 64];
  __shared__ short VTs[2][64 * 64];
  __shared__ short Pl[4][1024];
  const int tid = threadIdx.x, lane = tid & 63, wave = tid >> 6;
  const int l15 = lane & 15, lg = lane >> 4;
  // XCD swizzle: nwg=1024, xcd k gets heads [k*8, k*8+8)
  const int w = blockIdx.x;
  const int sw = (w & 7) * 128 + (w >> 3);
  const int bh = sw >> 4;
  const int q0 = (sw & 15) * 64 + wave * 16;

  const short* qp = Q + ((size_t)bh * S + q0 + l15) * DH + lg * 8;
  s16x8 qf0 = *(const s16x8*)qp;
  s16x8 qf1 = *(const s16x8*)(qp + 32);

  const short* kb = Km + (size_t)bh * S * DH;
  const short* vb = Vt + (size_t)bh * DH * S;
  short* myP = Pl[wave];
  const int rsz = (l15 & 7) << 3;   // frag-read XOR in shorts
  const s16x8 ones = { 0x3F80, 0x3F80, 0x3F80, 0x3F80, 0x3F80, 0x3F80, 0x3F80, 0x3F80 };

  stage_kv(kb, vb, 0, KT[0], VTs[0], tid);
  __syncthreads();

  f32x4 acc[4] = {};
  f32x4 accS = {};

  for (int kt = 0; kt < S; kt += 64) {
    const int cur = (kt >> 6) & 1;
    if (kt + 64 < S) stage_kv(kb, vb, kt + 64, KT[cur ^ 1], VTs[cur ^ 1], tid);

    // QK^T from LDS K tile (swizzled reads, conflict-free)
    f32x4 sf[4];
#pragma unroll
    for (int n = 0; n < 4; n++) {
      const short* kr = KT[cur] + (n * 16 + l15) * 64;
      s16x8 k0 = *(const s16x8*)(kr + ((lg * 8) ^ rsz));
      s16x8 k1 = *(const s16x8*)(kr + ((32 + lg * 8) ^ rsz));
      sf[n] = mfma_bf16(qf0, k0, f32x4{});
      sf[n] = mfma_bf16(qf1, k1, sf[n]);
    }

    // p = 2^s (scale folded into Q projection)
    f32x4 p[4];
#pragma unroll
    for (int n = 0; n < 4; n++)
#pragma unroll
      for (int i = 0; i < 4; i++) p[n][i] = exp2f(sf[n][i]);

    // P (C-layout) -> swizzled wave-private LDS -> A-layout fragments
#pragma unroll
    for (int n = 0; n < 4; n++)
#pragma unroll
      for (int i = 0; i < 4; i++) {
        int row = lg * 4 + i;
        myP[row * 64 + ((n * 16 + l15) ^ ((row & 7) << 3))] = f2bf(p[n][i]);
      }
    asm volatile("s_waitcnt lgkmcnt(0)" ::: "memory");
    s16x8 pa0 = *(const s16x8*)(myP + l15 * 64 + ((lg * 8) ^ rsz));
    s16x8 pa1 = *(const s16x8*)(myP + l15 * 64 + ((32 + lg * 8) ^ rsz));

    // row-sum of P via ones-MFMA (accumulates across tiles)
    accS = mfma_bf16(pa0, ones, accS);
    accS = mfma_bf16(pa1, ones, accS);

    // PV from LDS V^T tile
#pragma unroll
    for (int n = 0; n < 4; n++) {
      const short* vr = VTs[cur] + (n * 16 + l15) * 64;
      s16x8 v0 = *(const s16x8*)(vr + ((lg * 8) ^ rsz));
      s16x8 v1 = *(const s16x8*)(vr + ((32 + lg * 8) ^ rsz));
      acc[n] = mfma_bf16(pa0, v0, acc[n]);
      acc[n] = mfma_bf16(pa1, v1, acc[n]);
    }

    __syncthreads();   // stage(next) drained + all waves done with buf[cur]
  }

  float inv[4];
#pragma unroll
  for (int i = 0; i < 4; i++) inv[i] = 1.f / accS[i];
#pragma unroll
  for (int n = 0; n < 4; n++)
#pragma unroll
    for (int i = 0; i < 4; i++) {
      int qq = q0 + lg * 4 + i;
      int dc = n * 16 + l15;
      float v = acc[n][i] * inv[i];
      if (OUTMODE == 0)
        ((float*)outp)[((size_t)bh * S + qq) * DH + dc] = v;
      else
        ((short*)outp)[((size_t)(bh >> 4) * S + qq) * D + (bh & 15) * DH + dc] = f2bf(v);
    }
}

// ---------------- launch ----------------
extern "C" void kernel_launch(void* const* d_in, const int* in_sizes, int n_in,
                              void* d_out, int out_size, void* d_ws, size_t ws_size,
                              hipStream_t stream) {
  const float* xg = (const float*)d_in[0];
  const float* xl = (const float*)d_in[1];
  const float* xt = (const float*)d_in[2];
  const float* wf[7]; const float* bf_[7];
  for (int i = 0; i < 7; i++) { wf[i] = (const float*)d_in[3 + 2 * i]; bf_[i] = (const float*)d_in[4 + 2 * i]; }

  char* ws = (char*)d_ws;
  size_t off = 0;
  auto alloc = [&](size_t bytes) { void* p = ws + off; off += (bytes + 255) & ~(size_t)255; return p; };
  short* x16   = (short*)alloc((size_t)3 * M * KD * 2);
  short* w16   = (short*)alloc((size_t)7 * KD * ND * 2);
  short* gq16  = (short*)alloc((size_t)M * D * 2);
  short* gk16  = (short*)alloc((size_t)M * D * 2);
  float* gv32  = (float*)alloc((size_t)M * D * 4);
  short* pq16  = (short*)alloc((size_t)M * D * 2);
  short* pk16  = (short*)alloc((size_t)M * D * 2);
  short* pv16  = (short*)alloc((size_t)M * D * 2);
  short* pvt16 = (short*)alloc((size_t)M * D * 2);
  float* plb32 = (float*)alloc((size_t)M * D * 4);
  short* vpt16 = (short*)alloc((size_t)M * D * 2);
  short* last16= (short*)alloc((size_t)M * D * 2);
  (void)ws_size; (void)in_sizes; (void)n_in; (void)out_size;

  short* xg16 = x16;
  short* xl16 = x16 + (size_t)M * KD;
  short* xt16 = x16 + (size_t)2 * M * KD;

  Ptrs3 p3{xg, xl, xt};
  cast_inputs<<<3 * 4096, 256, 0, stream>>>(p3, x16);
  Ptrs7 p7; for (int i = 0; i < 7; i++) p7.p[i] = wf[i];
  cast_weights<<<7 * 1024, 256, 0, stream>>>(p7, w16);

  // Batched 6 projections: z = {gq*, gk, gv(f32), pq*, pk, pv}  (* = Q-scaled)
  GemmBatch gb;
  gb.A[0] = xg16; gb.A[1] = xl16; gb.A[2] = xl16; gb.A[3] = xl16; gb.A[4] = xt16; gb.A[5] = xt16;
  for (int i = 0; i < 6; i++) gb.bias[i] = bf_[i];
  gb.out[0] = gq16; gb.out[1] = gk16; gb.out[2] = gv32;
  gb.out[3] = pq16; gb.out[4] = pk16; gb.out[5] = pv16;
  gemm_proj<<<1536, 256, 0, stream>>>(gb, w16);

  dim3 gt(S / 64, NB * NH);        // (16, 64)
  transpose_bf16<<<gt, 256, 0, stream>>>(pv16, pvt16);
  attn64<0><<<1024, 256, 0, stream>>>(pq16, pk16, pvt16, plb32);   // plb_attn
  vprime_t<<<gt, 256, 0, stream>>>(gv32, plb32, vpt16);            // v' = gv + plb
  attn64<1><<<1024, 256, 0, stream>>>(gq16, gk16, vpt16, last16);  // last (merged)

  gemm_dense<<<256, 256, 0, stream>>>(last16, w16 + (size_t)6 * 1048576, bf_[6], (float*)d_out);
}

// Round 7
// 296.924 us; speedup vs baseline: 2.0786x; 1.0982x over previous
//
#include <hip/hip_runtime.h>

// Weird_Attention — exact algebraic restructure:
//   last = glb_probs @ (gv + softmax(pq pk^T/8) @ pv)
// => 6 proj GEMMs (batched) -> flash-attn(plb, +gv fused, writes v'^T)
//    -> flash-attn(glb, v') -> dense GEMM.
// R7: attn QBLK 32/wave (2x MFMA per barrier), vprime fused into attn<0>
// epilogue (gv now bf16 from gemm_proj), setprio around attn MFMA clusters.
// gemm_proj kept at 2-phase 128^2 (at its structural plateau; 8-phase port
// is the next structural step, pending this round's counters).

#define DEVI static __device__ __forceinline__

typedef __attribute__((ext_vector_type(4))) float f32x4;
typedef __attribute__((ext_vector_type(8))) __bf16 bf16x8;
typedef __attribute__((ext_vector_type(8))) short s16x8;
typedef __attribute__((ext_vector_type(4))) short s16x4;

constexpr int S = 1024, D = 1024, NH = 16, DH = 64, NB = 4;
constexpr int M = NB * S;
constexpr int KD = 1024;
constexpr int ND = 1024;
constexpr float QSCALE = 0.18033688011112042f;   // log2(e)/8

DEVI short f2bf(float f) {
  unsigned u = __builtin_bit_cast(unsigned, f);
  u += 0x7FFFu + ((u >> 16) & 1u);   // RNE
  return (short)(u >> 16);
}

DEVI f32x4 mfma_bf16(s16x8 a, s16x8 b, f32x4 c) {
  return __builtin_amdgcn_mfma_f32_16x16x32_bf16(
      __builtin_bit_cast(bf16x8, a), __builtin_bit_cast(bf16x8, b), c, 0, 0, 0);
}

DEVI void gll16(const void* g, void* l) {
  __builtin_amdgcn_global_load_lds(
      (const __attribute__((address_space(1))) unsigned*)g,
      (__attribute__((address_space(3))) unsigned*)l, 16, 0, 0);
}

DEVI float bf2f(short s) {
  unsigned u = (unsigned)(unsigned short)s << 16;
  return __builtin_bit_cast(float, u);
}

// ---------------- casts ----------------
struct Ptrs3 { const float* p0; const float* p1; const float* p2; };
struct Ptrs7 { const float* p[7]; };

__global__ __launch_bounds__(256) void cast_inputs(Ptrs3 in, short* __restrict__ out) {
  int b = blockIdx.x;                       // 3 * 4096 blocks
  int which = b >> 12;
  const float* src = which == 0 ? in.p0 : (which == 1 ? in.p1 : in.p2);
  size_t local = ((size_t)(b & 4095) * 256 + threadIdx.x) * 4;
  f32x4 v = *(const f32x4*)(src + local);
  s16x4 o = { f2bf(v[0]), f2bf(v[1]), f2bf(v[2]), f2bf(v[3]) };
  *(s16x4*)(out + (size_t)which * ((size_t)M * KD) + local) = o;
}

__global__ __launch_bounds__(256) void cast_weights(Ptrs7 in, short* __restrict__ out) {
  int b = blockIdx.x;                       // 7 * 1024 blocks
  int which = b >> 10;
  size_t local = ((size_t)(b & 1023) * 256 + threadIdx.x) * 4;
  f32x4 v = *(const f32x4*)(in.p[which] + local);
  s16x4 o = { f2bf(v[0]), f2bf(v[1]), f2bf(v[2]), f2bf(v[3]) };
  *(s16x4*)(out + (size_t)which * 1048576 + local) = o;
}

// -------- shared GEMM staging: 128x32 A-tile + 128x32 B-tile, swizzled ------
DEVI void stage_ab(const short* A, const short* Bw, int rowBase, int colBase, int k0,
                   short* Asb, short* Bsb, int tid) {
  const int cr = tid >> 2;
  const int cb = (tid & 3) * 16;           // byte chunk within 64B row
  const int sw = ((cr >> 1) & 3) << 4;     // same for cr and cr+64
  gll16((const char*)(A + (size_t)(rowBase + cr) * KD + k0) + (cb ^ sw), Asb + tid * 8);
  gll16((const char*)(A + (size_t)(rowBase + 64 + cr) * KD + k0) + (cb ^ sw), Asb + (tid + 256) * 8);
  gll16((const char*)(Bw + (size_t)(colBase + cr) * KD + k0) + (cb ^ sw), Bsb + tid * 8);
  gll16((const char*)(Bw + (size_t)(colBase + 64 + cr) * KD + k0) + (cb ^ sw), Bsb + (tid + 256) * 8);
}

// ------- batched projection GEMM: 6 C[M,N] = A@W^T + b, all bf16 out -------
struct GemmBatch {
  const short* A[6];
  const float* bias[6];
  short* out[6];
};

__global__ __launch_bounds__(256) void gemm_proj(GemmBatch gb, const short* __restrict__ W) {
  __shared__ short As[2][128 * 32];
  __shared__ short Bs[2][128 * 32];
  // bijective XCD swizzle over 1536 blocks (1536%8==0, cpx=192)
  const int wg = (blockIdx.x & 7) * 192 + (blockIdx.x >> 3);
  const int z = wg >> 8;
  const int rem = wg & 255;
  const int rowBase = (rem >> 3) * 128, colBase = (rem & 7) * 128;

  const short* A = gb.A[z];
  const short* Bw = W + (size_t)z * ((size_t)KD * ND);
  const float* bias = gb.bias[z];
  const float scale = (z == 0 || z == 3) ? QSCALE : 1.0f;

  const int tid = threadIdx.x;
  const int lane = tid & 63, wave = tid >> 6;
  const int wr = wave >> 1, wc = wave & 1;
  const int l15 = lane & 15, lg = lane >> 4;
  const int rs = ((l15 >> 1) & 3) << 3;    // frag-read XOR (shorts)

  stage_ab(A, Bw, rowBase, colBase, 0, As[0], Bs[0], tid);
  __syncthreads();

  f32x4 acc[4][4] = {};
  int buf = 0;
  for (int k0 = 0; k0 < KD; k0 += 32) {
    if (k0 + 32 < KD)
      stage_ab(A, Bw, rowBase, colBase, k0 + 32, As[buf ^ 1], Bs[buf ^ 1], tid);
    s16x8 af[4], bf[4];
#pragma unroll
    for (int m = 0; m < 4; m++)
      af[m] = *(const s16x8*)(As[buf] + (wr * 64 + m * 16 + l15) * 32 + ((lg * 8) ^ rs));
#pragma unroll
    for (int n = 0; n < 4; n++)
      bf[n] = *(const s16x8*)(Bs[buf] + (wc * 64 + n * 16 + l15) * 32 + ((lg * 8) ^ rs));
#pragma unroll
    for (int m = 0; m < 4; m++)
#pragma unroll
      for (int n = 0; n < 4; n++)
        acc[m][n] = mfma_bf16(af[m], bf[n], acc[m][n]);
    __syncthreads();
    buf ^= 1;
  }

  const int r0 = lg * 4;
#pragma unroll
  for (int m = 0; m < 4; m++)
#pragma unroll
    for (int n = 0; n < 4; n++)
#pragma unroll
      for (int i = 0; i < 4; i++) {
        int row = rowBase + wr * 64 + m * 16 + r0 + i;
        int col = colBase + wc * 64 + n * 16 + l15;
        float v = (acc[m][n][i] + bias[col]) * scale;
        size_t idx = (((size_t)(row >> 10) * NH + (col >> 6)) * S + (row & (S - 1))) * DH + (col & (DH - 1));
        gb.out[z][idx] = f2bf(v);
      }
}

// ---------------- dense GEMM: f32 [M,N] = A@W^T + b ----------------
__global__ __launch_bounds__(256) void gemm_dense(const short* __restrict__ A,
                                                  const short* __restrict__ Bw,
                                                  const float* __restrict__ bias,
                                                  float* __restrict__ outp) {
  __shared__ short As[2][128 * 32];
  __shared__ short Bs[2][128 * 32];
  const int wg = (blockIdx.x & 7) * 32 + (blockIdx.x >> 3);   // 256 blocks
  const int rowBase = (wg >> 3) * 128, colBase = (wg & 7) * 128;

  const int tid = threadIdx.x;
  const int lane = tid & 63, wave = tid >> 6;
  const int wr = wave >> 1, wc = wave & 1;
  const int l15 = lane & 15, lg = lane >> 4;
  const int rs = ((l15 >> 1) & 3) << 3;

  stage_ab(A, Bw, rowBase, colBase, 0, As[0], Bs[0], tid);
  __syncthreads();

  f32x4 acc[4][4] = {};
  int buf = 0;
  for (int k0 = 0; k0 < KD; k0 += 32) {
    if (k0 + 32 < KD)
      stage_ab(A, Bw, rowBase, colBase, k0 + 32, As[buf ^ 1], Bs[buf ^ 1], tid);
    s16x8 af[4], bf[4];
#pragma unroll
    for (int m = 0; m < 4; m++)
      af[m] = *(const s16x8*)(As[buf] + (wr * 64 + m * 16 + l15) * 32 + ((lg * 8) ^ rs));
#pragma unroll
    for (int n = 0; n < 4; n++)
      bf[n] = *(const s16x8*)(Bs[buf] + (wc * 64 + n * 16 + l15) * 32 + ((lg * 8) ^ rs));
#pragma unroll
    for (int m = 0; m < 4; m++)
#pragma unroll
      for (int n = 0; n < 4; n++)
        acc[m][n] = mfma_bf16(af[m], bf[n], acc[m][n]);
    __syncthreads();
    buf ^= 1;
  }

  const int r0 = lg * 4;
#pragma unroll
  for (int m = 0; m < 4; m++)
#pragma unroll
    for (int n = 0; n < 4; n++)
#pragma unroll
      for (int i = 0; i < 4; i++) {
        int row = rowBase + wr * 64 + m * 16 + r0 + i;
        int col = colBase + wc * 64 + n * 16 + l15;
        outp[(size_t)row * ND + col] = acc[m][n][i] + bias[col];
      }
}

// ---------------- transpose [BH,S,64] bf16 -> [BH,64,S] bf16 ----------------
__global__ __launch_bounds__(256) void transpose_bf16(const short* __restrict__ in,
                                                      short* __restrict__ out) {
  __shared__ short t[64 * 65];
  const int bh = blockIdx.y, s0 = blockIdx.x * 64;
  const int tid = threadIdx.x;
#pragma unroll
  for (int j = 0; j < 16; j++) {
    int e = j * 256 + tid;
    int s = e >> 6, d = e & 63;
    t[d * 65 + s] = in[((size_t)bh * S + s0 + s) * DH + d];
  }
  __syncthreads();
#pragma unroll
  for (int j = 0; j < 16; j++) {
    int e = j * 256 + tid;
    int d = e >> 6, s = e & 63;
    out[((size_t)bh * DH + d) * S + s0 + s] = t[d * 65 + s];
  }
}

// ---------------- flash attention (no-max softmax, LDS-staged K/V) ----------
// Q bf16 [BH,S,64] PRE-SCALED by log2(e)/8; K bf16 [BH,S,64]; Vt bf16 [BH,64,S].
// 4 waves/block, 32 q-rows/wave (128/block), 64-key tiles, 16 K-iters.
// p = exp2(s); O = acc / sum(p) via ones-MFMA.
// OUTMODE 0: epilogue adds gv (bf16 [BH,S,64]) and writes v' = gv+O
//            TRANSPOSED to [BH,64,S] bf16 (feeds attn<1> directly).
// OUTMODE 1: writes merged [B,S,D] bf16.
DEVI void stage_kv(const short* kb, const short* vb, int kt,
                   short* KT, short* VTs, int tid) {
  const int r0 = tid >> 3, cb = (tid & 7) * 16;
  const int r1 = r0 + 32;
  const int sw0 = (r0 & 7) << 4;   // r1&7 == r0&7
  gll16((const char*)kb + (size_t)(kt + r0) * 128 + (cb ^ sw0), KT + tid * 8);
  gll16((const char*)kb + (size_t)(kt + r1) * 128 + (cb ^ sw0), KT + (tid + 256) * 8);
  gll16((const char*)vb + (size_t)r0 * 2048 + (size_t)kt * 2 + (cb ^ sw0), VTs + tid * 8);
  gll16((const char*)vb + (size_t)r1 * 2048 + (size_t)kt * 2 + (cb ^ sw0), VTs + (tid + 256) * 8);
}

template <int OUTMODE>
__global__ __launch_bounds__(256, 2) void attn128(const short* __restrict__ Q,
                                                  const short* __restrict__ Km,
                                                  const short* __restrict__ Vt,
                                                  const short* __restrict__ gv,
                                                  void* __restrict__ outp) {
  __shared__ short KT[2][64 * 64];
  __shared__ short VTs[2][64 * 64];
  __shared__ short Pl[4][32 * 64];
  const int tid = threadIdx.x, lane = tid & 63, wave = tid >> 6;
  const int l15 = lane & 15, lg = lane >> 4;
  // bijective XCD swizzle: 512 blocks, xcd k gets heads [k*8,(k+1)*8)
  const int w = blockIdx.x;
  const int sw = (w & 7) * 64 + (w >> 3);
  const int bh = sw >> 3;
  const int q0 = (sw & 7) * 128 + wave * 32;   // this wave's first q-row

  s16x8 qf[2][2];
#pragma unroll
  for (int q = 0; q < 2; q++) {
    const short* qp = Q + ((size_t)bh * S + q0 + q * 16 + l15) * DH + lg * 8;
    qf[q][0] = *(const s16x8*)qp;
    qf[q][1] = *(const s16x8*)(qp + 32);
  }

  const short* kb = Km + (size_t)bh * S * DH;
  const short* vb = Vt + (size_t)bh * DH * S;
  short* myP = Pl[wave];
  const int rsz = (l15 & 7) << 3;   // frag-read XOR in shorts
  const s16x8 ones = { 0x3F80, 0x3F80, 0x3F80, 0x3F80, 0x3F80, 0x3F80, 0x3F80, 0x3F80 };

  stage_kv(kb, vb, 0, KT[0], VTs[0], tid);
  __syncthreads();

  f32x4 acc[2][4] = {};
  f32x4 accS[2] = {};

  for (int kt = 0; kt < S; kt += 64) {
    const int cur = (kt >> 6) & 1;
    if (kt + 64 < S) stage_kv(kb, vb, kt + 64, KT[cur ^ 1], VTs[cur ^ 1], tid);

    // QK^T from LDS K tile (swizzled reads, conflict-free)
    f32x4 sf[2][4];
    __builtin_amdgcn_s_setprio(1);
#pragma unroll
    for (int n = 0; n < 4; n++) {
      const short* kr = KT[cur] + (n * 16 + l15) * 64;
      s16x8 k0 = *(const s16x8*)(kr + ((lg * 8) ^ rsz));
      s16x8 k1 = *(const s16x8*)(kr + ((32 + lg * 8) ^ rsz));
#pragma unroll
      for (int q = 0; q < 2; q++) {
        sf[q][n] = mfma_bf16(qf[q][0], k0, f32x4{});
        sf[q][n] = mfma_bf16(qf[q][1], k1, sf[q][n]);
      }
    }
    __builtin_amdgcn_s_setprio(0);

    // p = 2^s (scale folded into Q projection), in place
#pragma unroll
    for (int q = 0; q < 2; q++)
#pragma unroll
      for (int n = 0; n < 4; n++)
#pragma unroll
        for (int i = 0; i < 4; i++) sf[q][n][i] = exp2f(sf[q][n][i]);

    // P (C-layout) -> swizzled wave-private LDS -> A-layout fragments
#pragma unroll
    for (int q = 0; q < 2; q++)
#pragma unroll
      for (int n = 0; n < 4; n++)
#pragma unroll
        for (int i = 0; i < 4; i++) {
          int row = q * 16 + lg * 4 + i;
          myP[row * 64 + ((n * 16 + l15) ^ ((row & 7) << 3))] = f2bf(sf[q][n][i]);
        }
    asm volatile("s_waitcnt lgkmcnt(0)" ::: "memory");
    __builtin_amdgcn_sched_barrier(0);
    s16x8 pa[2][2];
#pragma unroll
    for (int q = 0; q < 2; q++) {
      pa[q][0] = *(const s16x8*)(myP + (q * 16 + l15) * 64 + ((lg * 8) ^ rsz));
      pa[q][1] = *(const s16x8*)(myP + (q * 16 + l15) * 64 + ((32 + lg * 8) ^ rsz));
    }

    __builtin_amdgcn_s_setprio(1);
#pragma unroll
    for (int q = 0; q < 2; q++) {
      accS[q] = mfma_bf16(pa[q][0], ones, accS[q]);
      accS[q] = mfma_bf16(pa[q][1], ones, accS[q]);
    }
    // PV from LDS V^T tile (V-frags shared across both q halves)
#pragma unroll
    for (int n = 0; n < 4; n++) {
      const short* vr = VTs[cur] + (n * 16 + l15) * 64;
      s16x8 v0 = *(const s16x8*)(vr + ((lg * 8) ^ rsz));
      s16x8 v1 = *(const s16x8*)(vr + ((32 + lg * 8) ^ rsz));
#pragma unroll
      for (int q = 0; q < 2; q++) {
        acc[q][n] = mfma_bf16(pa[q][0], v0, acc[q][n]);
        acc[q][n] = mfma_bf16(pa[q][1], v1, acc[q][n]);
      }
    }
    __builtin_amdgcn_s_setprio(0);

    __syncthreads();   // stage(next) drained + all waves done with buf[cur]
  }

#pragma unroll
  for (int q = 0; q < 2; q++) {
    float inv[4];
#pragma unroll
    for (int i = 0; i < 4; i++) inv[i] = 1.f / accS[q][i];
#pragma unroll
    for (int n = 0; n < 4; n++) {
      const int dc = n * 16 + l15;
      if (OUTMODE == 0) {
        // v' = gv + O, written transposed [BH,64,S]
        const int qq0 = q0 + q * 16 + lg * 4;
        s16x4 o;
#pragma unroll
        for (int i = 0; i < 4; i++) {
          float g = bf2f(gv[((size_t)bh * S + qq0 + i) * DH + dc]);
          o[i] = f2bf(acc[q][n][i] * inv[i] + g);
        }
        *(s16x4*)((short*)outp + ((size_t)bh * DH + dc) * S + qq0) = o;
      } else {
#pragma unroll
        for (int i = 0; i < 4; i++) {
          int qq = q0 + q * 16 + lg * 4 + i;
          ((short*)outp)[((size_t)(bh >> 4) * S + qq) * D + (bh & 15) * DH + dc] =
              f2bf(acc[q][n][i] * inv[i]);
        }
      }
    }
  }
}

// ---------------- launch ----------------
extern "C" void kernel_launch(void* const* d_in, const int* in_sizes, int n_in,
                              void* d_out, int out_size, void* d_ws, size_t ws_size,
                              hipStream_t stream) {
  const float* xg = (const float*)d_in[0];
  const float* xl = (const float*)d_in[1];
  const float* xt = (const float*)d_in[2];
  const float* wf[7]; const float* bf_[7];
  for (int i = 0; i < 7; i++) { wf[i] = (const float*)d_in[3 + 2 * i]; bf_[i] = (const float*)d_in[4 + 2 * i]; }

  char* ws = (char*)d_ws;
  size_t off = 0;
  auto alloc = [&](size_t bytes) { void* p = ws + off; off += (bytes + 255) & ~(size_t)255; return p; };
  short* x16   = (short*)alloc((size_t)3 * M * KD * 2);
  short* w16   = (short*)alloc((size_t)7 * KD * ND * 2);
  short* gq16  = (short*)alloc((size_t)M * D * 2);
  short* gk16  = (short*)alloc((size_t)M * D * 2);
  short* gv16  = (short*)alloc((size_t)M * D * 2);
  short* pq16  = (short*)alloc((size_t)M * D * 2);
  short* pk16  = (short*)alloc((size_t)M * D * 2);
  short* pv16  = (short*)alloc((size_t)M * D * 2);
  short* pvt16 = (short*)alloc((size_t)M * D * 2);
  short* vpt16 = (short*)alloc((size_t)M * D * 2);
  short* last16= (short*)alloc((size_t)M * D * 2);
  (void)ws_size; (void)in_sizes; (void)n_in; (void)out_size;

  short* xg16 = x16;
  short* xl16 = x16 + (size_t)M * KD;
  short* xt16 = x16 + (size_t)2 * M * KD;

  Ptrs3 p3{xg, xl, xt};
  cast_inputs<<<3 * 4096, 256, 0, stream>>>(p3, x16);
  Ptrs7 p7; for (int i = 0; i < 7; i++) p7.p[i] = wf[i];
  cast_weights<<<7 * 1024, 256, 0, stream>>>(p7, w16);

  // Batched 6 projections: z = {gq*, gk, gv, pq*, pk, pv}  (* = Q-scaled)
  GemmBatch gb;
  gb.A[0] = xg16; gb.A[1] = xl16; gb.A[2] = xl16; gb.A[3] = xl16; gb.A[4] = xt16; gb.A[5] = xt16;
  for (int i = 0; i < 6; i++) gb.bias[i] = bf_[i];
  gb.out[0] = gq16; gb.out[1] = gk16; gb.out[2] = gv16;
  gb.out[3] = pq16; gb.out[4] = pk16; gb.out[5] = pv16;
  gemm_proj<<<1536, 256, 0, stream>>>(gb, w16);

  dim3 gt(S / 64, NB * NH);        // (16, 64)
  transpose_bf16<<<gt, 256, 0, stream>>>(pv16, pvt16);
  // plb attn, fused with v' = gv + plb_ctx, writes v'^T [BH,64,S]
  attn128<0><<<512, 256, 0, stream>>>(pq16, pk16, pvt16, gv16, vpt16);
  // glb attn on v', writes merged [B,S,D]
  attn128<1><<<512, 256, 0, stream>>>(gq16, gk16, vpt16, nullptr, last16);

  gemm_dense<<<256, 256, 0, stream>>>(last16, w16 + (size_t)6 * 1048576, bf_[6], (float*)d_out);
}

// Round 8
// 296.715 us; speedup vs baseline: 2.0801x; 1.0007x over previous
//
#include <hip/hip_runtime.h>

// Weird_Attention — exact algebraic restructure:
//   last = glb_probs @ (gv + softmax(pq pk^T/8) @ pv)
// => 6 proj GEMMs (batched) -> flash-attn(plb, +gv fused, writes v'^T)
//    -> flash-attn(glb, v') -> dense GEMM.
// R8: attn swapped QK^T (mfma(K,Q)) so P lands lane-local in k-contiguous
// groups of 4 -> P store is 8x ds_write_b64 instead of 32x ds_write_b16
// (write: 4 dwords/bank = b64 floor; read unchanged). Numerically identical.
// gemm_proj untouched this round (8-phase 256^2 port is next).

#define DEVI static __device__ __forceinline__

typedef __attribute__((ext_vector_type(4))) float f32x4;
typedef __attribute__((ext_vector_type(8))) __bf16 bf16x8;
typedef __attribute__((ext_vector_type(8))) short s16x8;
typedef __attribute__((ext_vector_type(4))) short s16x4;

constexpr int S = 1024, D = 1024, NH = 16, DH = 64, NB = 4;
constexpr int M = NB * S;
constexpr int KD = 1024;
constexpr int ND = 1024;
constexpr float QSCALE = 0.18033688011112042f;   // log2(e)/8

DEVI short f2bf(float f) {
  unsigned u = __builtin_bit_cast(unsigned, f);
  u += 0x7FFFu + ((u >> 16) & 1u);   // RNE
  return (short)(u >> 16);
}

DEVI f32x4 mfma_bf16(s16x8 a, s16x8 b, f32x4 c) {
  return __builtin_amdgcn_mfma_f32_16x16x32_bf16(
      __builtin_bit_cast(bf16x8, a), __builtin_bit_cast(bf16x8, b), c, 0, 0, 0);
}

DEVI void gll16(const void* g, void* l) {
  __builtin_amdgcn_global_load_lds(
      (const __attribute__((address_space(1))) unsigned*)g,
      (__attribute__((address_space(3))) unsigned*)l, 16, 0, 0);
}

DEVI float bf2f(short s) {
  unsigned u = (unsigned)(unsigned short)s << 16;
  return __builtin_bit_cast(float, u);
}

// ---------------- casts ----------------
struct Ptrs3 { const float* p0; const float* p1; const float* p2; };
struct Ptrs7 { const float* p[7]; };

__global__ __launch_bounds__(256) void cast_inputs(Ptrs3 in, short* __restrict__ out) {
  int b = blockIdx.x;                       // 3 * 4096 blocks
  int which = b >> 12;
  const float* src = which == 0 ? in.p0 : (which == 1 ? in.p1 : in.p2);
  size_t local = ((size_t)(b & 4095) * 256 + threadIdx.x) * 4;
  f32x4 v = *(const f32x4*)(src + local);
  s16x4 o = { f2bf(v[0]), f2bf(v[1]), f2bf(v[2]), f2bf(v[3]) };
  *(s16x4*)(out + (size_t)which * ((size_t)M * KD) + local) = o;
}

__global__ __launch_bounds__(256) void cast_weights(Ptrs7 in, short* __restrict__ out) {
  int b = blockIdx.x;                       // 7 * 1024 blocks
  int which = b >> 10;
  size_t local = ((size_t)(b & 1023) * 256 + threadIdx.x) * 4;
  f32x4 v = *(const f32x4*)(in.p[which] + local);
  s16x4 o = { f2bf(v[0]), f2bf(v[1]), f2bf(v[2]), f2bf(v[3]) };
  *(s16x4*)(out + (size_t)which * 1048576 + local) = o;
}

// -------- shared GEMM staging: 128x32 A-tile + 128x32 B-tile, swizzled ------
DEVI void stage_ab(const short* A, const short* Bw, int rowBase, int colBase, int k0,
                   short* Asb, short* Bsb, int tid) {
  const int cr = tid >> 2;
  const int cb = (tid & 3) * 16;           // byte chunk within 64B row
  const int sw = ((cr >> 1) & 3) << 4;     // same for cr and cr+64
  gll16((const char*)(A + (size_t)(rowBase + cr) * KD + k0) + (cb ^ sw), Asb + tid * 8);
  gll16((const char*)(A + (size_t)(rowBase + 64 + cr) * KD + k0) + (cb ^ sw), Asb + (tid + 256) * 8);
  gll16((const char*)(Bw + (size_t)(colBase + cr) * KD + k0) + (cb ^ sw), Bsb + tid * 8);
  gll16((const char*)(Bw + (size_t)(colBase + 64 + cr) * KD + k0) + (cb ^ sw), Bsb + (tid + 256) * 8);
}

// ------- batched projection GEMM: 6 C[M,N] = A@W^T + b, all bf16 out -------
struct GemmBatch {
  const short* A[6];
  const float* bias[6];
  short* out[6];
};

__global__ __launch_bounds__(256) void gemm_proj(GemmBatch gb, const short* __restrict__ W) {
  __shared__ short As[2][128 * 32];
  __shared__ short Bs[2][128 * 32];
  // bijective XCD swizzle over 1536 blocks (1536%8==0, cpx=192)
  const int wg = (blockIdx.x & 7) * 192 + (blockIdx.x >> 3);
  const int z = wg >> 8;
  const int rem = wg & 255;
  const int rowBase = (rem >> 3) * 128, colBase = (rem & 7) * 128;

  const short* A = gb.A[z];
  const short* Bw = W + (size_t)z * ((size_t)KD * ND);
  const float* bias = gb.bias[z];
  const float scale = (z == 0 || z == 3) ? QSCALE : 1.0f;

  const int tid = threadIdx.x;
  const int lane = tid & 63, wave = tid >> 6;
  const int wr = wave >> 1, wc = wave & 1;
  const int l15 = lane & 15, lg = lane >> 4;
  const int rs = ((l15 >> 1) & 3) << 3;    // frag-read XOR (shorts)

  stage_ab(A, Bw, rowBase, colBase, 0, As[0], Bs[0], tid);
  __syncthreads();

  f32x4 acc[4][4] = {};
  int buf = 0;
  for (int k0 = 0; k0 < KD; k0 += 32) {
    if (k0 + 32 < KD)
      stage_ab(A, Bw, rowBase, colBase, k0 + 32, As[buf ^ 1], Bs[buf ^ 1], tid);
    s16x8 af[4], bf[4];
#pragma unroll
    for (int m = 0; m < 4; m++)
      af[m] = *(const s16x8*)(As[buf] + (wr * 64 + m * 16 + l15) * 32 + ((lg * 8) ^ rs));
#pragma unroll
    for (int n = 0; n < 4; n++)
      bf[n] = *(const s16x8*)(Bs[buf] + (wc * 64 + n * 16 + l15) * 32 + ((lg * 8) ^ rs));
#pragma unroll
    for (int m = 0; m < 4; m++)
#pragma unroll
      for (int n = 0; n < 4; n++)
        acc[m][n] = mfma_bf16(af[m], bf[n], acc[m][n]);
    __syncthreads();
    buf ^= 1;
  }

  const int r0 = lg * 4;
#pragma unroll
  for (int m = 0; m < 4; m++)
#pragma unroll
    for (int n = 0; n < 4; n++)
#pragma unroll
      for (int i = 0; i < 4; i++) {
        int row = rowBase + wr * 64 + m * 16 + r0 + i;
        int col = colBase + wc * 64 + n * 16 + l15;
        float v = (acc[m][n][i] + bias[col]) * scale;
        size_t idx = (((size_t)(row >> 10) * NH + (col >> 6)) * S + (row & (S - 1))) * DH + (col & (DH - 1));
        gb.out[z][idx] = f2bf(v);
      }
}

// ---------------- dense GEMM: f32 [M,N] = A@W^T + b ----------------
__global__ __launch_bounds__(256) void gemm_dense(const short* __restrict__ A,
                                                  const short* __restrict__ Bw,
                                                  const float* __restrict__ bias,
                                                  float* __restrict__ outp) {
  __shared__ short As[2][128 * 32];
  __shared__ short Bs[2][128 * 32];
  const int wg = (blockIdx.x & 7) * 32 + (blockIdx.x >> 3);   // 256 blocks
  const int rowBase = (wg >> 3) * 128, colBase = (wg & 7) * 128;

  const int tid = threadIdx.x;
  const int lane = tid & 63, wave = tid >> 6;
  const int wr = wave >> 1, wc = wave & 1;
  const int l15 = lane & 15, lg = lane >> 4;
  const int rs = ((l15 >> 1) & 3) << 3;

  stage_ab(A, Bw, rowBase, colBase, 0, As[0], Bs[0], tid);
  __syncthreads();

  f32x4 acc[4][4] = {};
  int buf = 0;
  for (int k0 = 0; k0 < KD; k0 += 32) {
    if (k0 + 32 < KD)
      stage_ab(A, Bw, rowBase, colBase, k0 + 32, As[buf ^ 1], Bs[buf ^ 1], tid);
    s16x8 af[4], bf[4];
#pragma unroll
    for (int m = 0; m < 4; m++)
      af[m] = *(const s16x8*)(As[buf] + (wr * 64 + m * 16 + l15) * 32 + ((lg * 8) ^ rs));
#pragma unroll
    for (int n = 0; n < 4; n++)
      bf[n] = *(const s16x8*)(Bs[buf] + (wc * 64 + n * 16 + l15) * 32 + ((lg * 8) ^ rs));
#pragma unroll
    for (int m = 0; m < 4; m++)
#pragma unroll
      for (int n = 0; n < 4; n++)
        acc[m][n] = mfma_bf16(af[m], bf[n], acc[m][n]);
    __syncthreads();
    buf ^= 1;
  }

  const int r0 = lg * 4;
#pragma unroll
  for (int m = 0; m < 4; m++)
#pragma unroll
    for (int n = 0; n < 4; n++)
#pragma unroll
      for (int i = 0; i < 4; i++) {
        int row = rowBase + wr * 64 + m * 16 + r0 + i;
        int col = colBase + wc * 64 + n * 16 + l15;
        outp[(size_t)row * ND + col] = acc[m][n][i] + bias[col];
      }
}

// ---------------- transpose [BH,S,64] bf16 -> [BH,64,S] bf16 ----------------
__global__ __launch_bounds__(256) void transpose_bf16(const short* __restrict__ in,
                                                      short* __restrict__ out) {
  __shared__ short t[64 * 65];
  const int bh = blockIdx.y, s0 = blockIdx.x * 64;
  const int tid = threadIdx.x;
#pragma unroll
  for (int j = 0; j < 16; j++) {
    int e = j * 256 + tid;
    int s = e >> 6, d = e & 63;
    t[d * 65 + s] = in[((size_t)bh * S + s0 + s) * DH + d];
  }
  __syncthreads();
#pragma unroll
  for (int j = 0; j < 16; j++) {
    int e = j * 256 + tid;
    int d = e >> 6, s = e & 63;
    out[((size_t)bh * DH + d) * S + s0 + s] = t[d * 65 + s];
  }
}

// ---------------- flash attention (no-max softmax, LDS-staged K/V) ----------
// Q bf16 [BH,S,64] PRE-SCALED by log2(e)/8; K bf16 [BH,S,64]; Vt bf16 [BH,64,S].
// 4 waves/block, 32 q-rows/wave (128/block), 64-key tiles, 16 K-iters.
// Swapped QK^T: sf[q][n] = mfma(K_n, Q_q) -> lane holds P[q=l15][k=n*16+lg*4+i]
// (i contiguous) -> P stored with 8x ds_write_b64. p = exp2(s); O = acc/sum(p)
// via ones-MFMA on the A-layout P frags (C-layout row=q matches epilogue).
// OUTMODE 0: epilogue adds gv and writes v' = gv+O transposed [BH,64,S].
// OUTMODE 1: writes merged [B,S,D] bf16.
DEVI void stage_kv(const short* kb, const short* vb, int kt,
                   short* KT, short* VTs, int tid) {
  const int r0 = tid >> 3, cb = (tid & 7) * 16;
  const int r1 = r0 + 32;
  const int sw0 = (r0 & 7) << 4;   // r1&7 == r0&7
  gll16((const char*)kb + (size_t)(kt + r0) * 128 + (cb ^ sw0), KT + tid * 8);
  gll16((const char*)kb + (size_t)(kt + r1) * 128 + (cb ^ sw0), KT + (tid + 256) * 8);
  gll16((const char*)vb + (size_t)r0 * 2048 + (size_t)kt * 2 + (cb ^ sw0), VTs + tid * 8);
  gll16((const char*)vb + (size_t)r1 * 2048 + (size_t)kt * 2 + (cb ^ sw0), VTs + (tid + 256) * 8);
}

template <int OUTMODE>
__global__ __launch_bounds__(256, 2) void attn128(const short* __restrict__ Q,
                                                  const short* __restrict__ Km,
                                                  const short* __restrict__ Vt,
                                                  const short* __restrict__ gv,
                                                  void* __restrict__ outp) {
  __shared__ short KT[2][64 * 64];
  __shared__ short VTs[2][64 * 64];
  __shared__ short Pl[4][32 * 64];
  const int tid = threadIdx.x, lane = tid & 63, wave = tid >> 6;
  const int l15 = lane & 15, lg = lane >> 4;
  // bijective XCD swizzle: 512 blocks, xcd k gets heads [k*8,(k+1)*8)
  const int w = blockIdx.x;
  const int sw = (w & 7) * 64 + (w >> 3);
  const int bh = sw >> 3;
  const int q0 = (sw & 7) * 128 + wave * 32;   // this wave's first q-row

  s16x8 qf[2][2];
#pragma unroll
  for (int q = 0; q < 2; q++) {
    const short* qp = Q + ((size_t)bh * S + q0 + q * 16 + l15) * DH + lg * 8;
    qf[q][0] = *(const s16x8*)qp;
    qf[q][1] = *(const s16x8*)(qp + 32);
  }

  const short* kb = Km + (size_t)bh * S * DH;
  const short* vb = Vt + (size_t)bh * DH * S;
  short* myP = Pl[wave];
  const int rsz = (l15 & 7) << 3;   // row-based XOR in shorts (row&7 == l15&7)
  const s16x8 ones = { 0x3F80, 0x3F80, 0x3F80, 0x3F80, 0x3F80, 0x3F80, 0x3F80, 0x3F80 };

  stage_kv(kb, vb, 0, KT[0], VTs[0], tid);
  __syncthreads();

  f32x4 acc[2][4] = {};
  f32x4 accS[2] = {};

  for (int kt = 0; kt < S; kt += 64) {
    const int cur = (kt >> 6) & 1;
    if (kt + 64 < S) stage_kv(kb, vb, kt + 64, KT[cur ^ 1], VTs[cur ^ 1], tid);

    // Swapped QK^T: sf[q][n][i] = P[q_tile q][q=l15][k = n*16 + lg*4 + i]
    f32x4 sf[2][4];
    __builtin_amdgcn_s_setprio(1);
#pragma unroll
    for (int n = 0; n < 4; n++) {
      const short* kr = KT[cur] + (n * 16 + l15) * 64;
      s16x8 k0 = *(const s16x8*)(kr + ((lg * 8) ^ rsz));
      s16x8 k1 = *(const s16x8*)(kr + ((32 + lg * 8) ^ rsz));
#pragma unroll
      for (int q = 0; q < 2; q++) {
        sf[q][n] = mfma_bf16(k0, qf[q][0], f32x4{});
        sf[q][n] = mfma_bf16(k1, qf[q][1], sf[q][n]);
      }
    }
    __builtin_amdgcn_s_setprio(0);

    // p = 2^s (scale folded into Q projection), in place
#pragma unroll
    for (int q = 0; q < 2; q++)
#pragma unroll
      for (int n = 0; n < 4; n++)
#pragma unroll
        for (int i = 0; i < 4; i++) sf[q][n][i] = exp2f(sf[q][n][i]);

    // P row-major [32 q][64 k] in LDS, 8x ds_write_b64 (k-contiguous packs)
#pragma unroll
    for (int q = 0; q < 2; q++) {
      const int row = q * 16 + l15;
#pragma unroll
      for (int n = 0; n < 4; n++) {
        s16x4 o = { f2bf(sf[q][n][0]), f2bf(sf[q][n][1]),
                    f2bf(sf[q][n][2]), f2bf(sf[q][n][3]) };
        *(s16x4*)(myP + row * 64 + ((n * 16 + lg * 4) ^ rsz)) = o;
      }
    }
    asm volatile("s_waitcnt lgkmcnt(0)" ::: "memory");
    __builtin_amdgcn_sched_barrier(0);
    s16x8 pa[2][2];
#pragma unroll
    for (int q = 0; q < 2; q++) {
      pa[q][0] = *(const s16x8*)(myP + (q * 16 + l15) * 64 + ((lg * 8) ^ rsz));
      pa[q][1] = *(const s16x8*)(myP + (q * 16 + l15) * 64 + ((32 + lg * 8) ^ rsz));
    }

    __builtin_amdgcn_s_setprio(1);
#pragma unroll
    for (int q = 0; q < 2; q++) {
      accS[q] = mfma_bf16(pa[q][0], ones, accS[q]);
      accS[q] = mfma_bf16(pa[q][1], ones, accS[q]);
    }
    // PV from LDS V^T tile (V-frags shared across both q halves)
#pragma unroll
    for (int n = 0; n < 4; n++) {
      const short* vr = VTs[cur] + (n * 16 + l15) * 64;
      s16x8 v0 = *(const s16x8*)(vr + ((lg * 8) ^ rsz));
      s16x8 v1 = *(const s16x8*)(vr + ((32 + lg * 8) ^ rsz));
#pragma unroll
      for (int q = 0; q < 2; q++) {
        acc[q][n] = mfma_bf16(pa[q][0], v0, acc[q][n]);
        acc[q][n] = mfma_bf16(pa[q][1], v1, acc[q][n]);
      }
    }
    __builtin_amdgcn_s_setprio(0);

    __syncthreads();   // stage(next) drained + all waves done with buf[cur]
  }

#pragma unroll
  for (int q = 0; q < 2; q++) {
    float inv[4];
#pragma unroll
    for (int i = 0; i < 4; i++) inv[i] = 1.f / accS[q][i];
#pragma unroll
    for (int n = 0; n < 4; n++) {
      const int dc = n * 16 + l15;
      if (OUTMODE == 0) {
        // v' = gv + O, written transposed [BH,64,S]
        const int qq0 = q0 + q * 16 + lg * 4;
        s16x4 o;
#pragma unroll
        for (int i = 0; i < 4; i++) {
          float g = bf2f(gv[((size_t)bh * S + qq0 + i) * DH + dc]);
          o[i] = f2bf(acc[q][n][i] * inv[i] + g);
        }
        *(s16x4*)((short*)outp + ((size_t)bh * DH + dc) * S + qq0) = o;
      } else {
#pragma unroll
        for (int i = 0; i < 4; i++) {
          int qq = q0 + q * 16 + lg * 4 + i;
          ((short*)outp)[((size_t)(bh >> 4) * S + qq) * D + (bh & 15) * DH + dc] =
              f2bf(acc[q][n][i] * inv[i]);
        }
      }
    }
  }
}

// ---------------- launch ----------------
extern "C" void kernel_launch(void* const* d_in, const int* in_sizes, int n_in,
                              void* d_out, int out_size, void* d_ws, size_t ws_size,
                              hipStream_t stream) {
  const float* xg = (const float*)d_in[0];
  const float* xl = (const float*)d_in[1];
  const float* xt = (const float*)d_in[2];
  const float* wf[7]; const float* bf_[7];
  for (int i = 0; i < 7; i++) { wf[i] = (const float*)d_in[3 + 2 * i]; bf_[i] = (const float*)d_in[4 + 2 * i]; }

  char* ws = (char*)d_ws;
  size_t off = 0;
  auto alloc = [&](size_t bytes) { void* p = ws + off; off += (bytes + 255) & ~(size_t)255; return p; };
  short* x16   = (short*)alloc((size_t)3 * M * KD * 2);
  short* w16   = (short*)alloc((size_t)7 * KD * ND * 2);
  short* gq16  = (short*)alloc((size_t)M * D * 2);
  short* gk16  = (short*)alloc((size_t)M * D * 2);
  short* gv16  = (short*)alloc((size_t)M * D * 2);
  short* pq16  = (short*)alloc((size_t)M * D * 2);
  short* pk16  = (short*)alloc((size_t)M * D * 2);
  short* pv16  = (short*)alloc((size_t)M * D * 2);
  short* pvt16 = (short*)alloc((size_t)M * D * 2);
  short* vpt16 = (short*)alloc((size_t)M * D * 2);
  short* last16= (short*)alloc((size_t)M * D * 2);
  (void)ws_size; (void)in_sizes; (void)n_in; (void)out_size;

  short* xg16 = x16;
  short* xl16 = x16 + (size_t)M * KD;
  short* xt16 = x16 + (size_t)2 * M * KD;

  Ptrs3 p3{xg, xl, xt};
  cast_inputs<<<3 * 4096, 256, 0, stream>>>(p3, x16);
  Ptrs7 p7; for (int i = 0; i < 7; i++) p7.p[i] = wf[i];
  cast_weights<<<7 * 1024, 256, 0, stream>>>(p7, w16);

  // Batched 6 projections: z = {gq*, gk, gv, pq*, pk, pv}  (* = Q-scaled)
  GemmBatch gb;
  gb.A[0] = xg16; gb.A[1] = xl16; gb.A[2] = xl16; gb.A[3] = xl16; gb.A[4] = xt16; gb.A[5] = xt16;
  for (int i = 0; i < 6; i++) gb.bias[i] = bf_[i];
  gb.out[0] = gq16; gb.out[1] = gk16; gb.out[2] = gv16;
  gb.out[3] = pq16; gb.out[4] = pk16; gb.out[5] = pv16;
  gemm_proj<<<1536, 256, 0, stream>>>(gb, w16);

  dim3 gt(S / 64, NB * NH);        // (16, 64)
  transpose_bf16<<<gt, 256, 0, stream>>>(pv16, pvt16);
  // plb attn, fused with v' = gv + plb_ctx, writes v'^T [BH,64,S]
  attn128<0><<<512, 256, 0, stream>>>(pq16, pk16, pvt16, gv16, vpt16);
  // glb attn on v', writes merged [B,S,D]
  attn128<1><<<512, 256, 0, stream>>>(gq16, gk16, vpt16, nullptr, last16);

  gemm_dense<<<256, 256, 0, stream>>>(last16, w16 + (size_t)6 * 1048576, bf_[6], (float*)d_out);
}